// Round 10
// baseline (229.500 us; speedup 1.0000x reference)
//
#include <hip/hip_runtime.h>
#include <hip/hip_bf16.h>

#define BATCH   512
#define INDIM   768
#define HID     256
#define NGEN    4095
#define NGENP   4096
#define NOBS    15
#define OUTDIM  512
#define DIM     64

typedef __hip_bfloat16 bf16;

// static device scratch
__device__ int      g_isf32;
__device__ float    g_theta[(size_t)BATCH*NGENP];     // padded stride 4096
__device__ float    g_h[(size_t)BATCH*HID];
__device__ float    g_W2p[(size_t)HID*NGENP];
__device__ float    g_b2p[NGENP];

__device__ __forceinline__ float tof(bf16 v){ return __bfloat162float(v); }
__device__ __forceinline__ float silu(float x){ return x / (1.f + __expf(-x)); }
__device__ __forceinline__ float blo(unsigned u){ return __uint_as_float(u<<16); }
__device__ __forceinline__ float bhi(unsigned u){ return __uint_as_float(u & 0xFFFF0000u); }

template<bool F32>
__device__ __forceinline__ float LD(const void* p, size_t i){
  if(F32) return ((const float*)p)[i];
  else    return tof(((const bf16*)p)[i]);
}

// put bit p of x at bit 2p (6-bit input)
__device__ __forceinline__ unsigned spread6(unsigned x){
  return (x&1u) | ((x&2u)<<1) | ((x&4u)<<2) | ((x&8u)<<3) | ((x&16u)<<4) | ((x&32u)<<5);
}

// per-block dtype sniff (k_pack only; others read g_isf32)
__device__ __forceinline__ bool detect_f32(const unsigned* __restrict__ w1raw, int* red){
  const int t = threadIdx.x & (blockDim.x-1);
  const int lane = t & 63, wav = t >> 6;
  int c = 0;
  for(int i=t;i<1024;i+=(int)blockDim.x){
    unsigned ub = (w1raw[i]>>8) & 0x7Fu;
    if(ub>=0x30u && ub<=0x3Fu) c++;
  }
  #pragma unroll
  for(int s=1;s<64;s<<=1) c += __shfl_xor(c, s);
  if(lane==0) red[wav] = c;
  __syncthreads();
  int nw = (int)blockDim.x >> 6;
  int tot = 0;
  for(int w=0;w<nw;w++) tot += red[w];
  return tot < 512;
}

__constant__ int c_WA[15] = {0,0,0,0,0,1,1,1,1,2,2,2,3,3,4};
__constant__ int c_WB[15] = {1,2,3,4,5,2,3,4,5,3,4,5,4,5,5};
__constant__ int c_Lt[6]  = {1,2,2,3,3,3};
__constant__ int c_Kt[6]  = {0,0,1,0,1,2};

// ---- pack: detect (+publish g_isf32) + pack W2/b2 to f32.  Pure streaming. ----
template<bool F32>
__device__ void pack_body(const void* __restrict__ W2, const void* __restrict__ b2){
  const size_t gid = (size_t)blockIdx.x*256 + threadIdx.x;
  const size_t stride = (size_t)gridDim.x*256;
  for(size_t i=gid;i<(size_t)HID*NGENP;i+=stride){
    size_t k = i>>12, c = i&4095;
    g_W2p[i] = (c<NGEN) ? LD<F32>(W2,k*NGEN+c) : 0.f;
  }
  for(size_t i=gid;i<NGENP;i+=stride) g_b2p[i] = (i<NGEN) ? LD<F32>(b2,i) : 0.f;
}

__global__ __launch_bounds__(256) void k_pack(const void* W1,const void* W2,const void* b2){
  __shared__ int red[4];
  bool isf32 = detect_f32((const unsigned*)W1, red);
  if(blockIdx.x==0 && threadIdx.x==0) g_isf32 = isf32 ? 1 : 0;
  if(isf32) pack_body<true >(W2,b2);
  else      pack_body<false>(W2,b2);
}

// ---- enc1: h = silu(x@W1 + b1).  (R9-proven body) ----
template<bool F32>
__device__ void enc1_body(const void* __restrict__ x, const void* __restrict__ W1,
                          const void* __restrict__ b1, float* xl){
  const int b = blockIdx.x, t = threadIdx.x;
  for(int k=t;k<INDIM;k+=256) xl[k] = LD<F32>(x,(size_t)b*INDIM+k);
  __syncthreads();
  float acc = 0.f;
  float wA[8], wB[8];
  #pragma unroll
  for(int u=0;u<8;u++) wA[u] = LD<F32>(W1,(size_t)u*HID+t);
  for(int k0=0;k0<INDIM;k0+=16){
    #pragma unroll
    for(int u=0;u<8;u++) wB[u] = LD<F32>(W1,(size_t)(k0+8+u)*HID+t);
    #pragma unroll
    for(int u=0;u<8;u++) acc += xl[k0+u]*wA[u];
    if(k0+16<INDIM){
      #pragma unroll
      for(int u=0;u<8;u++) wA[u] = LD<F32>(W1,(size_t)(k0+16+u)*HID+t);
    }
    #pragma unroll
    for(int u=0;u<8;u++) acc += xl[k0+8+u]*wB[u];
  }
  g_h[(size_t)b*HID+t] = silu(acc + LD<F32>(b1,t));
}

__global__ __launch_bounds__(256) void k_enc1(const void* x,const void* W1,const void* b1){
  __shared__ __align__(16) float xl[INDIM];
  if(g_isf32) enc1_body<true >(x,W1,b1,xl);
  else        enc1_body<false>(x,W1,b1,xl);
}

// ---- enc2: theta = h@W2 + b2, register-tiled GEMM (R6-proven body) ----
__global__ __launch_bounds__(256) void k_enc2(){
  __shared__ __align__(16) float hl[HID][8];     // hl[k][r], 8KB, broadcast reads
  const int t  = threadIdx.x;
  const int b0 = (blockIdx.x>>2)*8;              // 64 row groups of 8
  const int c0 = (blockIdx.x&3)*1024;            // 4 col groups
  for(int i=t;i<8*HID;i+=256){
    int r = i>>8, k = i&255;
    hl[k][r] = g_h[(size_t)(b0+r)*HID + k];
  }
  __syncthreads();
  const int col = c0 + 4*t;
  const float* Wbase = g_W2p + col;
  float4 bv = *(const float4*)&g_b2p[col];
  float acc[8][4];
  #pragma unroll
  for(int r=0;r<8;r++){ acc[r][0]=bv.x; acc[r][1]=bv.y; acc[r][2]=bv.z; acc[r][3]=bv.w; }

  float4 wA[8], wB[8];
  #pragma unroll
  for(int u=0;u<8;u++) wA[u] = *(const float4*)&Wbase[(size_t)u*NGENP];

  for(int k0=0;k0<HID;k0+=16){
    #pragma unroll
    for(int u=0;u<8;u++) wB[u] = *(const float4*)&Wbase[(size_t)(k0+8+u)*NGENP];
    #pragma unroll
    for(int u=0;u<8;u++){
      float4 wv = wA[u];
      float4 h0 = *(const float4*)&hl[k0+u][0];
      float4 h1 = *(const float4*)&hl[k0+u][4];
      acc[0][0]+=h0.x*wv.x; acc[0][1]+=h0.x*wv.y; acc[0][2]+=h0.x*wv.z; acc[0][3]+=h0.x*wv.w;
      acc[1][0]+=h0.y*wv.x; acc[1][1]+=h0.y*wv.y; acc[1][2]+=h0.y*wv.z; acc[1][3]+=h0.y*wv.w;
      acc[2][0]+=h0.z*wv.x; acc[2][1]+=h0.z*wv.y; acc[2][2]+=h0.z*wv.z; acc[2][3]+=h0.z*wv.w;
      acc[3][0]+=h0.w*wv.x; acc[3][1]+=h0.w*wv.y; acc[3][2]+=h0.w*wv.z; acc[3][3]+=h0.w*wv.w;
      acc[4][0]+=h1.x*wv.x; acc[4][1]+=h1.x*wv.y; acc[4][2]+=h1.x*wv.z; acc[4][3]+=h1.x*wv.w;
      acc[5][0]+=h1.y*wv.x; acc[5][1]+=h1.y*wv.y; acc[5][2]+=h1.y*wv.z; acc[5][3]+=h1.y*wv.w;
      acc[6][0]+=h1.z*wv.x; acc[6][1]+=h1.z*wv.y; acc[6][2]+=h1.z*wv.z; acc[6][3]+=h1.z*wv.w;
      acc[7][0]+=h1.w*wv.x; acc[7][1]+=h1.w*wv.y; acc[7][2]+=h1.w*wv.z; acc[7][3]+=h1.w*wv.w;
    }
    if(k0+16 < HID){
      #pragma unroll
      for(int u=0;u<8;u++) wA[u] = *(const float4*)&Wbase[(size_t)(k0+16+u)*NGENP];
    }
    #pragma unroll
    for(int u=0;u<8;u++){
      float4 wv = wB[u];
      float4 h0 = *(const float4*)&hl[k0+8+u][0];
      float4 h1 = *(const float4*)&hl[k0+8+u][4];
      acc[0][0]+=h0.x*wv.x; acc[0][1]+=h0.x*wv.y; acc[0][2]+=h0.x*wv.z; acc[0][3]+=h0.x*wv.w;
      acc[1][0]+=h0.y*wv.x; acc[1][1]+=h0.y*wv.y; acc[1][2]+=h0.y*wv.z; acc[1][3]+=h0.y*wv.w;
      acc[2][0]+=h0.z*wv.x; acc[2][1]+=h0.z*wv.y; acc[2][2]+=h0.z*wv.z; acc[2][3]+=h0.z*wv.w;
      acc[3][0]+=h0.w*wv.x; acc[3][1]+=h0.w*wv.y; acc[3][2]+=h0.w*wv.z; acc[3][3]+=h0.w*wv.w;
      acc[4][0]+=h1.x*wv.x; acc[4][1]+=h1.x*wv.y; acc[4][2]+=h1.x*wv.z; acc[4][3]+=h1.x*wv.w;
      acc[5][0]+=h1.y*wv.x; acc[5][1]+=h1.y*wv.y; acc[5][2]+=h1.y*wv.z; acc[5][3]+=h1.y*wv.w;
      acc[6][0]+=h1.z*wv.x; acc[6][1]+=h1.z*wv.y; acc[6][2]+=h1.z*wv.z; acc[6][3]+=h1.z*wv.w;
      acc[7][0]+=h1.w*wv.x; acc[7][1]+=h1.w*wv.y; acc[7][2]+=h1.w*wv.z; acc[7][3]+=h1.w*wv.w;
    }
  }
  #pragma unroll
  for(int r=0;r<8;r++){
    float4 o = make_float4(acc[r][0],acc[r][1],acc[r][2],acc[r][3]);
    *(float4*)&g_theta[(size_t)(b0+r)*NGENP + col] = o;
  }
}

// -------- state: 512 threads/block (8 waves -> 16 waves/CU at 2 blocks/CU).
// 8 lanes per matrix row: per-thread matvec work halves vs R9, and after the
// xor-reduce ALL lanes hold the dot product, so every lane updates its own
// v/ps replica (8 replicas, stride 66 -> broadcast reads) -- no c==0 divergence.
// LDS region A [0,16384): th during WHT, then small buffers.  Region B: HH
// during WHT/init, then hl+part overlay (HH dead after w1 init).
template<bool F32>
__device__ void state_body(const void* __restrict__ Aoff, const void* __restrict__ Boff,
                           const void* __restrict__ Ddiag,
                           const void* __restrict__ Wv1, const void* __restrict__ bv1,
                           const void* __restrict__ Wv2, const void* __restrict__ bv2,
                           void* __restrict__ out, char* sm){
  float*  th   = (float*)sm;                        // [0,16380) during WHT
  typedef float2 rep_t[66];
  rep_t*  vrA  = (rep_t*)sm;                        // 8*528 = 4224
  rep_t*  vrB  = (rep_t*)(sm + 4224);               // 4224 -> 8448
  float2 (*ps4)[66] = (float2(*)[66])(sm + 8448);   // 8*528 = 4224 -> 12672
  float2* coef = (float2*)(sm + 12672);             // 1216 -> 13888
  float*  rs   = (float*)(sm + 13888);              // 256 -> 14144
  float*  qacc = (float*)(sm + 14144);              // 64 -> 14208
  float*  s_inva = (float*)(sm + 14208);
  int*    s_K    = (int*)(sm + 14212);
  float*  s2p  = (float*)(sm + 14224);              // 32 -> 14256
  float*  HH   = (float*)(sm + 16384);              // 64*132*4 = 33792 -> 50176
  float*  hl   = (float*)(sm + 16384);              // overlay (HH dead by vel head)
  float (*part)[64][8] = (float(*)[64][8])(sm + 17408); // 8192 -> 25600

  const int b = blockIdx.x, t = threadIdx.x;
  float s2l = 0.f;
  for(int m=t;m<NGEN;m+=512){
    float v = g_theta[(size_t)b*NGENP+m];
    th[m] = v;
    s2l += v*v;
  }
  __syncthreads();

  const int lane = t & 63, wav = t >> 6;            // 8 waves
  for(int it=0; it<8; ++it){
    int d = (it<<3) | wav;
    unsigned td = (unsigned)(lane & d);
    unsigned tn = (unsigned)(lane & ~d) & 63u;
    unsigned w  = spread6((unsigned)d) + spread6(td) + 3u*spread6(tn);
    float thv = (w==0u) ? 0.f : th[w-1u];
    int ny = __popc(td) & 3;
    float gr = (ny==0)?  thv : (ny==2 ? -thv : 0.f);
    float gi = (ny==1)? -thv : (ny==3 ?  thv : 0.f);
    #pragma unroll
    for(int s=1;s<64;s<<=1){
      float pr = __shfl_xor(gr, s);
      float pi = __shfl_xor(gi, s);
      if(lane & s){ gr = pr - gr; gi = pi - gi; }
      else        { gr = gr + pr; gi = gi + pi; }
    }
    int j = lane ^ d;
    HH[lane*132 + 2*j]   = gr;
    HH[lane*132 + 2*j+1] = gi;
  }
  __syncthreads();          // th region dead; small buffers live there now

  const int i = t >> 3, c = t & 7, j0 = c*8;        // 8 lanes per row
  float hreg[16];
  float rsum = 0.f;
  #pragma unroll
  for(int jj=0;jj<8;jj+=2){
    float4 hv = *(const float4*)&HH[i*132 + 2*(j0+jj)];
    hreg[2*jj+0]=hv.x; hreg[2*jj+1]=hv.y; hreg[2*jj+2]=hv.z; hreg[2*jj+3]=hv.w;
    rsum += fabsf(hv.x)+fabsf(hv.y)+fabsf(hv.z)+fabsf(hv.w);
  }
  rsum += __shfl_xor(rsum,1);
  rsum += __shfl_xor(rsum,2);
  rsum += __shfl_xor(rsum,4);
  if(c==0) rs[i] = rsum;
  // full-wave reduce of theta^2 partial
  #pragma unroll
  for(int s=1;s<64;s<<=1) s2l += __shfl_xor(s2l, s);
  if(lane==0) s2p[wav] = s2l;
  __syncthreads();

  // ---- a = min(Gershgorin, 2.3*sqrt(sum theta^2)); Bessel coefficients ----
  if(t==0){
    float aG = 0.5f;
    for(int r=0;r<DIM;r++) aG = fmaxf(aG, rs[r]);
    float s2tot = 0.f;
    for(int w2=0;w2<8;w2++) s2tot += s2p[w2];
    float a = fminf(aG, fmaxf(2.3f*sqrtf(s2tot), 0.5f));
    int K = (int)ceilf(a + 4.f*cbrtf(a) + 5.f);
    if(K>150) K=150;
    float bkp=0.f, bk=1e-35f, snorm=0.f;
    for(int k=K+12;k>=1;--k){
      float bkm = (2.f*(float)k/a)*bk - bkp;
      int n = k-1;
      if(n<=K) coef[n].x = bkm;
      if((n&1)==0) snorm += (n==0?1.f:2.f)*bkm;
      bkp = bk; bk = bkm;
    }
    float invs = 1.f/snorm;
    for(int n=0;n<=K;n++){
      float cv = coef[n].x*invs*(n==0?1.f:2.f);
      int p = n&3;
      float cr = (p==0)? cv : (p==2 ? -cv : 0.f);
      float ci = (p==1)? cv : (p==3 ? -cv : 0.f);
      coef[n] = make_float2(cr,ci);
    }
    *s_K = K;
    *s_inva = 1.f/a;
  }
  __syncthreads();
  const float inva = *s_inva;
  const int K = *s_K;

  rep_t* v0r = vrA;
  rep_t* v1r = vrB;
  {
    // every (i,c) thread initializes its own replica slot -- bitwise-equal replicas
    float2 w1 = make_float2(HH[i*132+0]*inva, HH[i*132+1]*inva);
    float2 e0 = make_float2(i==0?1.f:0.f, 0.f);
    v0r[c][i] = e0;
    v1r[c][i] = w1;
    float2 c0 = coef[0], c1 = coef[1];
    float2 p;
    p.x = (i==0?c0.x:0.f) + c1.x*w1.x - c1.y*w1.y;
    p.y = (i==0?c0.y:0.f) + c1.x*w1.y + c1.y*w1.x;
    ps4[c][i] = p;
  }
  __syncthreads();

  for(int k=2;k<=K;k++){
    const float* vb = (const float*)&v1r[c][0];
    float yr=0.f, yi=0.f;
    #pragma unroll
    for(int jj=0;jj<8;jj+=2){
      float4 xv = *(const float4*)&vb[2*(j0+jj)];
      float hr0=hreg[2*jj], hi0=hreg[2*jj+1], hr1=hreg[2*jj+2], hi1=hreg[2*jj+3];
      yr += hr0*xv.x - hi0*xv.y;
      yi += hr0*xv.y + hi0*xv.x;
      yr += hr1*xv.z - hi1*xv.w;
      yi += hr1*xv.w + hi1*xv.z;
    }
    yr += __shfl_xor(yr,1); yr += __shfl_xor(yr,2); yr += __shfl_xor(yr,4);
    yi += __shfl_xor(yi,1); yi += __shfl_xor(yi,2); yi += __shfl_xor(yi,4);
    // all 8 lanes hold the full dot product: update own replica, no divergence
    float2 vm = v0r[c][i];
    float2 vn = make_float2(2.f*inva*yr - vm.x, 2.f*inva*yi - vm.y);
    v0r[c][i] = vn;
    float2 ck = coef[k];
    float2 p = ps4[c][i];
    p.x += ck.x*vn.x - ck.y*vn.y;
    p.y += ck.x*vn.y + ck.y*vn.x;
    ps4[c][i] = p;
    __syncthreads();
    rep_t* tmp = v0r; v0r = v1r; v1r = tmp;
  }

  const float2* ps = &ps4[0][0];
  if(t<NOBS) qacc[t]=0.f;
  __syncthreads();

  if(t<150){
    int w = t/10, s = t%10;
    int posA = 5 - c_WA[w], posB = 5 - c_WB[w];
    float contrib = 0.f;
    bool have = false;
    if(s<4){
      int kk = s;
      if(kk<3){
        float val = 0.f;
        for(int r=0;r<16;r++){
          int idx = (((kk>>1)&1)<<posA) | ((kk&1)<<posB);
          int rb = 3;
          #pragma unroll
          for(int p=5;p>=0;--p){
            if(p==posA || p==posB) continue;
            idx |= ((r>>rb)&1)<<p;
            rb--;
          }
          float2 pv = ps[idx];
          val += pv.x*pv.x + pv.y*pv.y;
        }
        contrib = val*2.f*LD<F32>(Ddiag, w*4 + kk + 1);
        have = true;
      }
    } else {
      int cc = s-4;
      int l = c_Lt[cc], kk = c_Kt[cc];
      float zr=0.f, zi=0.f;
      for(int r=0;r<16;r++){
        int idxk = (((kk>>1)&1)<<posA) | ((kk&1)<<posB);
        int idxl = (((l >>1)&1)<<posA) | ((l &1)<<posB);
        int rb = 3;
        #pragma unroll
        for(int p=5;p>=0;--p){
          if(p==posA || p==posB) continue;
          int bit = (r>>rb)&1;
          idxk |= bit<<p; idxl |= bit<<p;
          rb--;
        }
        float2 pk = ps[idxk], pl = ps[idxl];
        zr += pk.x*pl.x + pk.y*pl.y;
        zi += pk.y*pl.x - pk.x*pl.y;
      }
      contrib = 2.f*(zr*LD<F32>(Aoff,w*6+cc) - zi*LD<F32>(Boff,w*6+cc));
      have = true;
    }
    if(have) atomicAdd(&qacc[w], contrib);
  }
  __syncthreads();

  // ---------- FUSED vel head (exact R8 256-thread structure, guarded) ----------
  if(!F32){
    if(t<HID){
      float acc = tof(((const bf16*)bv1)[t]);
      #pragma unroll
      for(int k=0;k<NOBS;k++) acc += qacc[k]*tof(((const bf16*)Wv1)[k*HID+t]);
      hl[t] = silu(acc);
    }
    __syncthreads();
    if(t<256){
      const int rg = t >> 6;                     // k-chunk 0..3
      const uint4* w2v = (const uint4*)Wv2;      // row = 64 uint4 (512 cols)
      float a8[8] = {0.f,0.f,0.f,0.f,0.f,0.f,0.f,0.f};
      for(int kk=0; kk<64; kk+=8){
        uint4 wv[8];
        #pragma unroll
        for(int u=0;u<8;u++) wv[u] = w2v[(size_t)(rg*64+kk+u)*64 + lane];
        #pragma unroll
        for(int u=0;u<8;u++){
          float hk = hl[rg*64+kk+u];
          a8[0] += hk*blo(wv[u].x); a8[1] += hk*bhi(wv[u].x);
          a8[2] += hk*blo(wv[u].y); a8[3] += hk*bhi(wv[u].y);
          a8[4] += hk*blo(wv[u].z); a8[5] += hk*bhi(wv[u].z);
          a8[6] += hk*blo(wv[u].w); a8[7] += hk*bhi(wv[u].w);
        }
      }
      #pragma unroll
      for(int j=0;j<8;j++) part[rg][lane][j] = a8[j];
    }
    __syncthreads();
    if(t<256){
      int cA = 2*t, cB = 2*t+1;
      float vA = tof(((const bf16*)bv2)[cA]);
      float vB = tof(((const bf16*)bv2)[cB]);
      #pragma unroll
      for(int r2=0;r2<4;r2++){
        vA += part[r2][cA>>3][cA&7];
        vB += part[r2][cB>>3][cB&7];
      }
      bf16 ha = __float2bfloat16(vA), hb = __float2bfloat16(vB);
      unsigned pw = (unsigned)(*(unsigned short*)&ha) |
                    ((unsigned)(*(unsigned short*)&hb)<<16);
      ((unsigned*)out)[(size_t)b*(OUTDIM/2) + t] = pw;
    }
  } else {
    if(t<HID){
      float acc = ((const float*)bv1)[t];
      #pragma unroll
      for(int k=0;k<NOBS;k++) acc += qacc[k]*((const float*)Wv1)[k*HID+t];
      hl[t] = silu(acc);
    }
    __syncthreads();
    if(t<256){
      #pragma unroll
      for(int oo=0;oo<2;oo++){
        int o = t + oo*256;
        float s0=0.f;
        for(int k=0;k<HID;k++) s0 += hl[k]*((const float*)Wv2)[(size_t)k*OUTDIM+o];
        ((float*)out)[(size_t)b*OUTDIM+o] = ((const float*)bv2)[o] + s0;
      }
    }
  }
}

__global__ __launch_bounds__(512) void k_state(const void* Aoff,const void* Boff,const void* Dd,
                                               const void* Wv1,const void* bv1,
                                               const void* Wv2,const void* bv2, void* out){
  __shared__ __align__(16) char sm[50176];   // shared by both template paths
  if(g_isf32) state_body<true >(Aoff,Boff,Dd,Wv1,bv1,Wv2,bv2,out,sm);
  else        state_body<false>(Aoff,Boff,Dd,Wv1,bv1,Wv2,bv2,out,sm);
}

extern "C" void kernel_launch(void* const* d_in, const int* in_sizes, int n_in,
                              void* d_out, int out_size, void* d_ws, size_t ws_size,
                              hipStream_t stream){
  const void* x    = d_in[0];
  const void* W1   = d_in[1];
  const void* b1   = d_in[2];
  const void* W2   = d_in[3];
  const void* b2   = d_in[4];
  const void* Aoff = d_in[5];
  const void* Boff = d_in[6];
  const void* Dd   = d_in[7];
  const void* Wv1  = d_in[8];
  const void* bv1  = d_in[9];
  const void* Wv2  = d_in[10];
  const void* bv2  = d_in[11];
  // d_in[12] (pauli) unused: H_eff built analytically from the Pauli-word structure.

  k_pack <<<1024,256,0,stream>>>(W1,W2,b2);
  k_enc1 <<<BATCH,256,0,stream>>>(x,W1,b1);
  k_enc2 <<<256,256,0,stream>>>();
  k_state<<<BATCH,512,0,stream>>>(Aoff,Boff,Dd,Wv1,bv1,Wv2,bv2,d_out);
}

// Round 11
// 226.332 us; speedup vs baseline: 1.0140x; 1.0140x over previous
//
#include <hip/hip_runtime.h>
#include <hip/hip_bf16.h>

#define BATCH   512
#define INDIM   768
#define HID     256
#define NGEN    4095
#define NGENP   4096
#define NOBS    15
#define OUTDIM  512
#define DIM     64

typedef __hip_bfloat16 bf16;

// static device scratch
__device__ int      g_isf32;
__device__ float    g_theta[(size_t)BATCH*NGENP];     // padded stride 4096
__device__ float    g_h[(size_t)BATCH*HID];
__device__ float    g_W2p[(size_t)HID*NGENP];
__device__ float    g_b2p[NGENP];

__device__ __forceinline__ float tof(bf16 v){ return __bfloat162float(v); }
__device__ __forceinline__ float silu(float x){ return x / (1.f + __expf(-x)); }
__device__ __forceinline__ float blo(unsigned u){ return __uint_as_float(u<<16); }
__device__ __forceinline__ float bhi(unsigned u){ return __uint_as_float(u & 0xFFFF0000u); }

template<bool F32>
__device__ __forceinline__ float LD(const void* p, size_t i){
  if(F32) return ((const float*)p)[i];
  else    return tof(((const bf16*)p)[i]);
}

// put bit p of x at bit 2p (6-bit input)
__device__ __forceinline__ unsigned spread6(unsigned x){
  return (x&1u) | ((x&2u)<<1) | ((x&4u)<<2) | ((x&8u)<<3) | ((x&16u)<<4) | ((x&32u)<<5);
}

// per-block dtype sniff (k_pack only; others read g_isf32)
__device__ __forceinline__ bool detect_f32(const unsigned* __restrict__ w1raw, int* red){
  const int t = threadIdx.x & (blockDim.x-1);
  const int lane = t & 63, wav = t >> 6;
  int c = 0;
  for(int i=t;i<1024;i+=(int)blockDim.x){
    unsigned ub = (w1raw[i]>>8) & 0x7Fu;
    if(ub>=0x30u && ub<=0x3Fu) c++;
  }
  #pragma unroll
  for(int s=1;s<64;s<<=1) c += __shfl_xor(c, s);
  if(lane==0) red[wav] = c;
  __syncthreads();
  int nw = (int)blockDim.x >> 6;
  int tot = 0;
  for(int w=0;w<nw;w++) tot += red[w];
  return tot < 512;
}

__constant__ int c_WA[15] = {0,0,0,0,0,1,1,1,1,2,2,2,3,3,4};
__constant__ int c_WB[15] = {1,2,3,4,5,2,3,4,5,3,4,5,4,5,5};
__constant__ int c_Lt[6]  = {1,2,2,3,3,3};
__constant__ int c_Kt[6]  = {0,0,1,0,1,2};

// ---- pack: detect (+publish g_isf32) + pack W2/b2 to f32.  Pure streaming. ----
template<bool F32>
__device__ void pack_body(const void* __restrict__ W2, const void* __restrict__ b2){
  const size_t gid = (size_t)blockIdx.x*256 + threadIdx.x;
  const size_t stride = (size_t)gridDim.x*256;
  for(size_t i=gid;i<(size_t)HID*NGENP;i+=stride){
    size_t k = i>>12, c = i&4095;
    g_W2p[i] = (c<NGEN) ? LD<F32>(W2,k*NGEN+c) : 0.f;
  }
  for(size_t i=gid;i<NGENP;i+=stride) g_b2p[i] = (i<NGEN) ? LD<F32>(b2,i) : 0.f;
}

__global__ __launch_bounds__(256) void k_pack(const void* W1,const void* W2,const void* b2){
  __shared__ int red[4];
  bool isf32 = detect_f32((const unsigned*)W1, red);
  if(blockIdx.x==0 && threadIdx.x==0) g_isf32 = isf32 ? 1 : 0;
  if(isf32) pack_body<true >(W2,b2);
  else      pack_body<false>(W2,b2);
}

// ---- enc1: h = silu(x@W1 + b1).  (R9-proven body) ----
template<bool F32>
__device__ void enc1_body(const void* __restrict__ x, const void* __restrict__ W1,
                          const void* __restrict__ b1, float* xl){
  const int b = blockIdx.x, t = threadIdx.x;
  for(int k=t;k<INDIM;k+=256) xl[k] = LD<F32>(x,(size_t)b*INDIM+k);
  __syncthreads();
  float acc = 0.f;
  float wA[8], wB[8];
  #pragma unroll
  for(int u=0;u<8;u++) wA[u] = LD<F32>(W1,(size_t)u*HID+t);
  for(int k0=0;k0<INDIM;k0+=16){
    #pragma unroll
    for(int u=0;u<8;u++) wB[u] = LD<F32>(W1,(size_t)(k0+8+u)*HID+t);
    #pragma unroll
    for(int u=0;u<8;u++) acc += xl[k0+u]*wA[u];
    if(k0+16<INDIM){
      #pragma unroll
      for(int u=0;u<8;u++) wA[u] = LD<F32>(W1,(size_t)(k0+16+u)*HID+t);
    }
    #pragma unroll
    for(int u=0;u<8;u++) acc += xl[k0+8+u]*wB[u];
  }
  g_h[(size_t)b*HID+t] = silu(acc + LD<F32>(b1,t));
}

__global__ __launch_bounds__(256) void k_enc1(const void* x,const void* W1,const void* b1){
  __shared__ __align__(16) float xl[INDIM];
  if(g_isf32) enc1_body<true >(x,W1,b1,xl);
  else        enc1_body<false>(x,W1,b1,xl);
}

// ---- enc2: theta = h@W2 + b2, register-tiled GEMM (R6-proven body) ----
__global__ __launch_bounds__(256) void k_enc2(){
  __shared__ __align__(16) float hl[HID][8];     // hl[k][r], 8KB, broadcast reads
  const int t  = threadIdx.x;
  const int b0 = (blockIdx.x>>2)*8;              // 64 row groups of 8
  const int c0 = (blockIdx.x&3)*1024;            // 4 col groups
  for(int i=t;i<8*HID;i+=256){
    int r = i>>8, k = i&255;
    hl[k][r] = g_h[(size_t)(b0+r)*HID + k];
  }
  __syncthreads();
  const int col = c0 + 4*t;
  const float* Wbase = g_W2p + col;
  float4 bv = *(const float4*)&g_b2p[col];
  float acc[8][4];
  #pragma unroll
  for(int r=0;r<8;r++){ acc[r][0]=bv.x; acc[r][1]=bv.y; acc[r][2]=bv.z; acc[r][3]=bv.w; }

  float4 wA[8], wB[8];
  #pragma unroll
  for(int u=0;u<8;u++) wA[u] = *(const float4*)&Wbase[(size_t)u*NGENP];

  for(int k0=0;k0<HID;k0+=16){
    #pragma unroll
    for(int u=0;u<8;u++) wB[u] = *(const float4*)&Wbase[(size_t)(k0+8+u)*NGENP];
    #pragma unroll
    for(int u=0;u<8;u++){
      float4 wv = wA[u];
      float4 h0 = *(const float4*)&hl[k0+u][0];
      float4 h1 = *(const float4*)&hl[k0+u][4];
      acc[0][0]+=h0.x*wv.x; acc[0][1]+=h0.x*wv.y; acc[0][2]+=h0.x*wv.z; acc[0][3]+=h0.x*wv.w;
      acc[1][0]+=h0.y*wv.x; acc[1][1]+=h0.y*wv.y; acc[1][2]+=h0.y*wv.z; acc[1][3]+=h0.y*wv.w;
      acc[2][0]+=h0.z*wv.x; acc[2][1]+=h0.z*wv.y; acc[2][2]+=h0.z*wv.z; acc[2][3]+=h0.z*wv.w;
      acc[3][0]+=h0.w*wv.x; acc[3][1]+=h0.w*wv.y; acc[3][2]+=h0.w*wv.z; acc[3][3]+=h0.w*wv.w;
      acc[4][0]+=h1.x*wv.x; acc[4][1]+=h1.x*wv.y; acc[4][2]+=h1.x*wv.z; acc[4][3]+=h1.x*wv.w;
      acc[5][0]+=h1.y*wv.x; acc[5][1]+=h1.y*wv.y; acc[5][2]+=h1.y*wv.z; acc[5][3]+=h1.y*wv.w;
      acc[6][0]+=h1.z*wv.x; acc[6][1]+=h1.z*wv.y; acc[6][2]+=h1.z*wv.z; acc[6][3]+=h1.z*wv.w;
      acc[7][0]+=h1.w*wv.x; acc[7][1]+=h1.w*wv.y; acc[7][2]+=h1.w*wv.z; acc[7][3]+=h1.w*wv.w;
    }
    if(k0+16 < HID){
      #pragma unroll
      for(int u=0;u<8;u++) wA[u] = *(const float4*)&Wbase[(size_t)(k0+16+u)*NGENP];
    }
    #pragma unroll
    for(int u=0;u<8;u++){
      float4 wv = wB[u];
      float4 h0 = *(const float4*)&hl[k0+8+u][0];
      float4 h1 = *(const float4*)&hl[k0+8+u][4];
      acc[0][0]+=h0.x*wv.x; acc[0][1]+=h0.x*wv.y; acc[0][2]+=h0.x*wv.z; acc[0][3]+=h0.x*wv.w;
      acc[1][0]+=h0.y*wv.x; acc[1][1]+=h0.y*wv.y; acc[1][2]+=h0.y*wv.z; acc[1][3]+=h0.y*wv.w;
      acc[2][0]+=h0.z*wv.x; acc[2][1]+=h0.z*wv.y; acc[2][2]+=h0.z*wv.z; acc[2][3]+=h0.z*wv.w;
      acc[3][0]+=h0.w*wv.x; acc[3][1]+=h0.w*wv.y; acc[3][2]+=h0.w*wv.z; acc[3][3]+=h0.w*wv.w;
      acc[4][0]+=h1.x*wv.x; acc[4][1]+=h1.x*wv.y; acc[4][2]+=h1.x*wv.z; acc[4][3]+=h1.x*wv.w;
      acc[5][0]+=h1.y*wv.x; acc[5][1]+=h1.y*wv.y; acc[5][2]+=h1.y*wv.z; acc[5][3]+=h1.y*wv.w;
      acc[6][0]+=h1.z*wv.x; acc[6][1]+=h1.z*wv.y; acc[6][2]+=h1.z*wv.z; acc[6][3]+=h1.z*wv.w;
      acc[7][0]+=h1.w*wv.x; acc[7][1]+=h1.w*wv.y; acc[7][2]+=h1.w*wv.z; acc[7][3]+=h1.w*wv.w;
    }
  }
  #pragma unroll
  for(int r=0;r<8;r++){
    float4 o = make_float4(acc[r][0],acc[r][1],acc[r][2],acc[r][3]);
    *(float4*)&g_theta[(size_t)(b0+r)*NGENP + col] = o;
  }
}

// -------- state: R9-proven 256-thread body + (a) K = a+3.5cbrt(a)+4 (tail ~2e-6,
// 1% of output quantum), (b) tail loads (obs scalars, Wv1/bv1/bv2) hoisted to top
// so their latency hides under WHT+Chebyshev, (c) Wv2 double-buffered in vel head.
template<bool F32>
__device__ void state_body(const void* __restrict__ Aoff, const void* __restrict__ Boff,
                           const void* __restrict__ Ddiag,
                           const void* __restrict__ Wv1, const void* __restrict__ bv1,
                           const void* __restrict__ Wv2, const void* __restrict__ bv2,
                           void* __restrict__ out, char* sm){
  float*  th   = (float*)sm;                       // 16KB region, dead after WHT
  float*  HH   = (float*)(sm + 16384);             // 64*132 f
  typedef float2 rep_t[66];
  rep_t*  vrA  = (rep_t*)sm;                       // 2112 B
  rep_t*  vrB  = (rep_t*)(sm + 2112);              // 2112 B
  float2* ps   = (float2*)(sm + 4224);             // 512 B
  float2* coef = (float2*)(sm + 4736);             // 1280 B
  float*  rs   = (float*)(sm + 6016);              // 256 B
  float*  qacc = (float*)(sm + 6272);              // 64 B
  float*  s_inva = (float*)(sm + 6336);
  int*    s_K    = (int*)(sm + 6340);
  float*  hl   = (float*)(sm + 6400);              // 1KB   (fused vel)
  float (*part)[64][8] = (float(*)[64][8])(sm + 7424); // 8KB -> ends 15616
  float*  s2p  = (float*)(sm + 15616);             // 16 B (per-wave theta^2 partials)

  const int b = blockIdx.x, t = threadIdx.x;
  const int lane = t & 63, wav = t >> 6;

  float s2l = 0.f;
  for(int m=t;m<NGEN;m+=256){
    float v = g_theta[(size_t)b*NGENP+m];
    th[m] = v;
    s2l += v*v;
  }

  // ---- hoisted tail loads: latency hides under the WHT + Chebyshev phases ----
  float obs_d = 0.f, obs_a = 0.f, obs_b = 0.f;
  {
    int w = t/10, s = t%10;
    if(t<150){
      if(s<3)        obs_d = LD<F32>(Ddiag, w*4 + s + 1);
      else if(s>=4){ obs_a = LD<F32>(Aoff, w*6 + s-4);
                     obs_b = LD<F32>(Boff, w*6 + s-4); }
    }
  }
  float wv1h[NOBS], bv1h, bv2lo = 0.f, bv2hi = 0.f;
  if(!F32){
    bv1h = tof(((const bf16*)bv1)[t]);
    #pragma unroll
    for(int k=0;k<NOBS;k++) wv1h[k] = tof(((const bf16*)Wv1)[k*HID+t]);
    unsigned bp = ((const unsigned*)bv2)[t];
    bv2lo = blo(bp); bv2hi = bhi(bp);
  } else {
    bv1h = ((const float*)bv1)[t];
    #pragma unroll
    for(int k=0;k<NOBS;k++) wv1h[k] = ((const float*)Wv1)[k*HID+t];
  }
  __syncthreads();

  #pragma unroll 4
  for(int it=0; it<16; ++it){
    int d = (it<<2) | wav;
    unsigned td = (unsigned)(lane & d);
    unsigned tn = (unsigned)(lane & ~d) & 63u;
    unsigned w  = spread6((unsigned)d) + spread6(td) + 3u*spread6(tn);
    float thv = (w==0u) ? 0.f : th[w-1u];
    int ny = __popc(td) & 3;
    float gr = (ny==0)?  thv : (ny==2 ? -thv : 0.f);
    float gi = (ny==1)? -thv : (ny==3 ?  thv : 0.f);
    #pragma unroll
    for(int s=1;s<64;s<<=1){
      float pr = __shfl_xor(gr, s);
      float pi = __shfl_xor(gi, s);
      if(lane & s){ gr = pr - gr; gi = pi - gi; }
      else        { gr = gr + pr; gi = gi + pi; }
    }
    int j = lane ^ d;
    HH[lane*132 + 2*j]   = gr;
    HH[lane*132 + 2*j+1] = gi;
  }
  __syncthreads();          // th region dead; small buffers live there now

  const int i = t >> 2, c = t & 3, j0 = c*16;
  float hreg[32];
  float rsum = 0.f;
  #pragma unroll
  for(int jj=0;jj<16;jj+=2){
    float4 hv = *(const float4*)&HH[i*132 + 2*(j0+jj)];
    hreg[2*jj+0]=hv.x; hreg[2*jj+1]=hv.y; hreg[2*jj+2]=hv.z; hreg[2*jj+3]=hv.w;
    rsum += fabsf(hv.x)+fabsf(hv.y)+fabsf(hv.z)+fabsf(hv.w);
  }
  rsum += __shfl_xor(rsum,1);
  rsum += __shfl_xor(rsum,2);
  if(c==0) rs[i] = rsum;
  // full-wave reduce of theta^2 partial
  #pragma unroll
  for(int s=1;s<64;s<<=1) s2l += __shfl_xor(s2l, s);
  if(lane==0) s2p[wav] = s2l;
  __syncthreads();

  // ---- a = min(Gershgorin, 2.3*sqrt(sum theta^2)); Bessel coefficients ----
  if(t==0){
    float aG = 0.5f;
    for(int r=0;r<DIM;r++) aG = fmaxf(aG, rs[r]);
    float s2tot = s2p[0]+s2p[1]+s2p[2]+s2p[3];
    float a = fminf(aG, fmaxf(2.3f*sqrtf(s2tot), 0.5f));
    int K = (int)ceilf(a + 3.5f*cbrtf(a) + 4.f);
    if(K>150) K=150;
    float bkp=0.f, bk=1e-35f, snorm=0.f;
    for(int k=K+12;k>=1;--k){
      float bkm = (2.f*(float)k/a)*bk - bkp;
      int n = k-1;
      if(n<=K) coef[n].x = bkm;
      if((n&1)==0) snorm += (n==0?1.f:2.f)*bkm;
      bkp = bk; bk = bkm;
    }
    float invs = 1.f/snorm;
    for(int n=0;n<=K;n++){
      float cv = coef[n].x*invs*(n==0?1.f:2.f);
      int p = n&3;
      float cr = (p==0)? cv : (p==2 ? -cv : 0.f);
      float ci = (p==1)? cv : (p==3 ? -cv : 0.f);
      coef[n] = make_float2(cr,ci);
    }
    *s_K = K;
    *s_inva = 1.f/a;
  }
  __syncthreads();
  const float inva = *s_inva;
  const int K = *s_K;

  rep_t* v0r = vrA;
  rep_t* v1r = vrB;
  if(t < DIM){
    float2 w1 = make_float2(HH[t*132+0]*inva, HH[t*132+1]*inva);
    float2 e0 = make_float2(t==0?1.f:0.f, 0.f);
    #pragma unroll
    for(int cc=0;cc<4;cc++){ v0r[cc][t] = e0; v1r[cc][t] = w1; }
    float2 c0 = coef[0], c1 = coef[1];
    float2 p;
    p.x = (t==0?c0.x:0.f) + c1.x*w1.x - c1.y*w1.y;
    p.y = (t==0?c0.y:0.f) + c1.x*w1.y + c1.y*w1.x;
    ps[t] = p;
  }
  __syncthreads();

  for(int k=2;k<=K;k++){
    const float* vb = (const float*)&v1r[c][0];
    float yr=0.f, yi=0.f;
    #pragma unroll
    for(int jj=0;jj<16;jj+=2){
      float4 xv = *(const float4*)&vb[2*(j0+jj)];
      float hr0=hreg[2*jj], hi0=hreg[2*jj+1], hr1=hreg[2*jj+2], hi1=hreg[2*jj+3];
      yr += hr0*xv.x - hi0*xv.y;
      yi += hr0*xv.y + hi0*xv.x;
      yr += hr1*xv.z - hi1*xv.w;
      yi += hr1*xv.w + hi1*xv.z;
    }
    yr += __shfl_xor(yr,1); yr += __shfl_xor(yr,2);
    yi += __shfl_xor(yi,1); yi += __shfl_xor(yi,2);
    if(c==0){
      float2 vm = v0r[0][i];
      float2 vn = make_float2(2.f*inva*yr - vm.x, 2.f*inva*yi - vm.y);
      #pragma unroll
      for(int cc=0;cc<4;cc++) v0r[cc][i] = vn;
      float2 ck = coef[k];
      float2 p = ps[i];
      p.x += ck.x*vn.x - ck.y*vn.y;
      p.y += ck.x*vn.y + ck.y*vn.x;
      ps[i] = p;
    }
    __syncthreads();
    rep_t* tmp = v0r; v0r = v1r; v1r = tmp;
  }

  if(t<NOBS) qacc[t]=0.f;
  __syncthreads();

  if(t<150){
    int w = t/10, s = t%10;
    int posA = 5 - c_WA[w], posB = 5 - c_WB[w];
    float contrib = 0.f;
    bool have = false;
    if(s<4){
      int kk = s;
      if(kk<3){
        float val = 0.f;
        for(int r=0;r<16;r++){
          int idx = (((kk>>1)&1)<<posA) | ((kk&1)<<posB);
          int rb = 3;
          #pragma unroll
          for(int p=5;p>=0;--p){
            if(p==posA || p==posB) continue;
            idx |= ((r>>rb)&1)<<p;
            rb--;
          }
          float2 pv = ps[idx];
          val += pv.x*pv.x + pv.y*pv.y;
        }
        contrib = val*2.f*obs_d;
        have = true;
      }
    } else {
      int cc = s-4;
      int l = c_Lt[cc], kk = c_Kt[cc];
      float zr=0.f, zi=0.f;
      for(int r=0;r<16;r++){
        int idxk = (((kk>>1)&1)<<posA) | ((kk&1)<<posB);
        int idxl = (((l >>1)&1)<<posA) | ((l &1)<<posB);
        int rb = 3;
        #pragma unroll
        for(int p=5;p>=0;--p){
          if(p==posA || p==posB) continue;
          int bit = (r>>rb)&1;
          idxk |= bit<<p; idxl |= bit<<p;
          rb--;
        }
        float2 pk = ps[idxk], pl = ps[idxl];
        zr += pk.x*pl.x + pk.y*pl.y;
        zi += pk.y*pl.x - pk.x*pl.y;
      }
      contrib = 2.f*(zr*obs_a - zi*obs_b);
      have = true;
    }
    if(have) atomicAdd(&qacc[w], contrib);
  }
  __syncthreads();

  // ---------- FUSED vel head (both dtypes; Wv1/bv1/bv2 preloaded) ----------
  if(!F32){
    {
      float acc = bv1h;
      #pragma unroll
      for(int k=0;k<NOBS;k++) acc += qacc[k]*wv1h[k];
      hl[t] = silu(acc);
    }
    __syncthreads();
    const int rg = t >> 6;                     // k-chunk 0..3
    const uint4* w2v = (const uint4*)Wv2;      // row = 64 uint4 (512 cols)
    float a8[8] = {0.f,0.f,0.f,0.f,0.f,0.f,0.f,0.f};
    uint4 wvA[8], wvB[8];
    #pragma unroll
    for(int u=0;u<8;u++) wvA[u] = w2v[(size_t)(rg*64+u)*64 + lane];
    for(int kk=0; kk<64; kk+=16){
      #pragma unroll
      for(int u=0;u<8;u++) wvB[u] = w2v[(size_t)(rg*64+kk+8+u)*64 + lane];
      #pragma unroll
      for(int u=0;u<8;u++){
        float hk = hl[rg*64+kk+u];
        a8[0] += hk*blo(wvA[u].x); a8[1] += hk*bhi(wvA[u].x);
        a8[2] += hk*blo(wvA[u].y); a8[3] += hk*bhi(wvA[u].y);
        a8[4] += hk*blo(wvA[u].z); a8[5] += hk*bhi(wvA[u].z);
        a8[6] += hk*blo(wvA[u].w); a8[7] += hk*bhi(wvA[u].w);
      }
      if(kk+16 < 64){
        #pragma unroll
        for(int u=0;u<8;u++) wvA[u] = w2v[(size_t)(rg*64+kk+16+u)*64 + lane];
      }
      #pragma unroll
      for(int u=0;u<8;u++){
        float hk = hl[rg*64+kk+8+u];
        a8[0] += hk*blo(wvB[u].x); a8[1] += hk*bhi(wvB[u].x);
        a8[2] += hk*blo(wvB[u].y); a8[3] += hk*bhi(wvB[u].y);
        a8[4] += hk*blo(wvB[u].z); a8[5] += hk*bhi(wvB[u].z);
        a8[6] += hk*blo(wvB[u].w); a8[7] += hk*bhi(wvB[u].w);
      }
    }
    #pragma unroll
    for(int j=0;j<8;j++) part[rg][lane][j] = a8[j];
    __syncthreads();
    {
      int cA = 2*t, cB = 2*t+1;
      float vA = bv2lo;
      float vB = bv2hi;
      #pragma unroll
      for(int r2=0;r2<4;r2++){
        vA += part[r2][cA>>3][cA&7];
        vB += part[r2][cB>>3][cB&7];
      }
      bf16 ha = __float2bfloat16(vA), hb = __float2bfloat16(vB);
      unsigned pw = (unsigned)(*(unsigned short*)&ha) |
                    ((unsigned)(*(unsigned short*)&hb)<<16);
      ((unsigned*)out)[(size_t)b*(OUTDIM/2) + t] = pw;
    }
  } else {
    {
      float acc = bv1h;
      #pragma unroll
      for(int k=0;k<NOBS;k++) acc += qacc[k]*wv1h[k];
      hl[t] = silu(acc);
    }
    __syncthreads();
    #pragma unroll
    for(int oo=0;oo<2;oo++){
      int o = t + oo*256;
      float s0=0.f;
      for(int k=0;k<HID;k++) s0 += hl[k]*((const float*)Wv2)[(size_t)k*OUTDIM+o];
      ((float*)out)[(size_t)b*OUTDIM+o] = ((const float*)bv2)[o] + s0;
    }
  }
}

__global__ __launch_bounds__(256) void k_state(const void* Aoff,const void* Boff,const void* Dd,
                                               const void* Wv1,const void* bv1,
                                               const void* Wv2,const void* bv2, void* out){
  __shared__ __align__(16) char sm[50176];   // shared by both template paths
  if(g_isf32) state_body<true >(Aoff,Boff,Dd,Wv1,bv1,Wv2,bv2,out,sm);
  else        state_body<false>(Aoff,Boff,Dd,Wv1,bv1,Wv2,bv2,out,sm);
}

extern "C" void kernel_launch(void* const* d_in, const int* in_sizes, int n_in,
                              void* d_out, int out_size, void* d_ws, size_t ws_size,
                              hipStream_t stream){
  const void* x    = d_in[0];
  const void* W1   = d_in[1];
  const void* b1   = d_in[2];
  const void* W2   = d_in[3];
  const void* b2   = d_in[4];
  const void* Aoff = d_in[5];
  const void* Boff = d_in[6];
  const void* Dd   = d_in[7];
  const void* Wv1  = d_in[8];
  const void* bv1  = d_in[9];
  const void* Wv2  = d_in[10];
  const void* bv2  = d_in[11];
  // d_in[12] (pauli) unused: H_eff built analytically from the Pauli-word structure.

  k_pack <<<1024,256,0,stream>>>(W1,W2,b2);
  k_enc1 <<<BATCH,256,0,stream>>>(x,W1,b1);
  k_enc2 <<<256,256,0,stream>>>();
  k_state<<<BATCH,256,0,stream>>>(Aoff,Boff,Dd,Wv1,bv1,Wv2,bv2,d_out);
}

// Round 12
// 223.477 us; speedup vs baseline: 1.0270x; 1.0128x over previous
//
#include <hip/hip_runtime.h>
#include <hip/hip_bf16.h>

#define BATCH   512
#define INDIM   768
#define HID     256
#define NGEN    4095
#define NGENP   4096
#define NOBS    15
#define OUTDIM  512
#define DIM     64

typedef __hip_bfloat16 bf16;

// static device scratch
__device__ int      g_isf32;
__device__ float    g_theta[(size_t)BATCH*NGENP];     // padded stride 4096
__device__ float    g_h[(size_t)BATCH*HID];
__device__ float    g_W2p[(size_t)HID*NGENP];
__device__ float    g_b2p[NGENP];

__device__ __forceinline__ float tof(bf16 v){ return __bfloat162float(v); }
__device__ __forceinline__ float silu(float x){ return x / (1.f + __expf(-x)); }
__device__ __forceinline__ float blo(unsigned u){ return __uint_as_float(u<<16); }
__device__ __forceinline__ float bhi(unsigned u){ return __uint_as_float(u & 0xFFFF0000u); }

template<bool F32>
__device__ __forceinline__ float LD(const void* p, size_t i){
  if(F32) return ((const float*)p)[i];
  else    return tof(((const bf16*)p)[i]);
}

// put bit p of x at bit 2p (6-bit input)
__device__ __forceinline__ unsigned spread6(unsigned x){
  return (x&1u) | ((x&2u)<<1) | ((x&4u)<<2) | ((x&8u)<<3) | ((x&16u)<<4) | ((x&32u)<<5);
}

// per-block dtype sniff (k_pack only; others read g_isf32)
__device__ __forceinline__ bool detect_f32(const unsigned* __restrict__ w1raw, int* red){
  const int t = threadIdx.x & (blockDim.x-1);
  const int lane = t & 63, wav = t >> 6;
  int c = 0;
  for(int i=t;i<1024;i+=(int)blockDim.x){
    unsigned ub = (w1raw[i]>>8) & 0x7Fu;
    if(ub>=0x30u && ub<=0x3Fu) c++;
  }
  #pragma unroll
  for(int s=1;s<64;s<<=1) c += __shfl_xor(c, s);
  if(lane==0) red[wav] = c;
  __syncthreads();
  int nw = (int)blockDim.x >> 6;
  int tot = 0;
  for(int w=0;w<nw;w++) tot += red[w];
  return tot < 512;
}

__constant__ int c_WA[15] = {0,0,0,0,0,1,1,1,1,2,2,2,3,3,4};
__constant__ int c_WB[15] = {1,2,3,4,5,2,3,4,5,3,4,5,4,5,5};
__constant__ int c_Lt[6]  = {1,2,2,3,3,3};
__constant__ int c_Kt[6]  = {0,0,1,0,1,2};

// ---- pack: detect (+publish g_isf32) + pack W2/b2 to f32.  Pure streaming. ----
template<bool F32>
__device__ void pack_body(const void* __restrict__ W2, const void* __restrict__ b2){
  const size_t gid = (size_t)blockIdx.x*256 + threadIdx.x;
  const size_t stride = (size_t)gridDim.x*256;
  for(size_t i=gid;i<(size_t)HID*NGENP;i+=stride){
    size_t k = i>>12, c = i&4095;
    g_W2p[i] = (c<NGEN) ? LD<F32>(W2,k*NGEN+c) : 0.f;
  }
  for(size_t i=gid;i<NGENP;i+=stride) g_b2p[i] = (i<NGEN) ? LD<F32>(b2,i) : 0.f;
}

__global__ __launch_bounds__(256) void k_pack(const void* W1,const void* W2,const void* b2){
  __shared__ int red[4];
  bool isf32 = detect_f32((const unsigned*)W1, red);
  if(blockIdx.x==0 && threadIdx.x==0) g_isf32 = isf32 ? 1 : 0;
  if(isf32) pack_body<true >(W2,b2);
  else      pack_body<false>(W2,b2);
}

// ---- enc1: h = silu(x@W1 + b1).  (R9-proven body) ----
template<bool F32>
__device__ void enc1_body(const void* __restrict__ x, const void* __restrict__ W1,
                          const void* __restrict__ b1, float* xl){
  const int b = blockIdx.x, t = threadIdx.x;
  for(int k=t;k<INDIM;k+=256) xl[k] = LD<F32>(x,(size_t)b*INDIM+k);
  __syncthreads();
  float acc = 0.f;
  float wA[8], wB[8];
  #pragma unroll
  for(int u=0;u<8;u++) wA[u] = LD<F32>(W1,(size_t)u*HID+t);
  for(int k0=0;k0<INDIM;k0+=16){
    #pragma unroll
    for(int u=0;u<8;u++) wB[u] = LD<F32>(W1,(size_t)(k0+8+u)*HID+t);
    #pragma unroll
    for(int u=0;u<8;u++) acc += xl[k0+u]*wA[u];
    if(k0+16<INDIM){
      #pragma unroll
      for(int u=0;u<8;u++) wA[u] = LD<F32>(W1,(size_t)(k0+16+u)*HID+t);
    }
    #pragma unroll
    for(int u=0;u<8;u++) acc += xl[k0+8+u]*wB[u];
  }
  g_h[(size_t)b*HID+t] = silu(acc + LD<F32>(b1,t));
}

__global__ __launch_bounds__(256) void k_enc1(const void* x,const void* W1,const void* b1){
  __shared__ __align__(16) float xl[INDIM];
  if(g_isf32) enc1_body<true >(x,W1,b1,xl);
  else        enc1_body<false>(x,W1,b1,xl);
}

// ---- enc2: theta = h@W2 + b2, register-tiled GEMM (R6-proven body) ----
__global__ __launch_bounds__(256) void k_enc2(){
  __shared__ __align__(16) float hl[HID][8];     // hl[k][r], 8KB, broadcast reads
  const int t  = threadIdx.x;
  const int b0 = (blockIdx.x>>2)*8;              // 64 row groups of 8
  const int c0 = (blockIdx.x&3)*1024;            // 4 col groups
  for(int i=t;i<8*HID;i+=256){
    int r = i>>8, k = i&255;
    hl[k][r] = g_h[(size_t)(b0+r)*HID + k];
  }
  __syncthreads();
  const int col = c0 + 4*t;
  const float* Wbase = g_W2p + col;
  float4 bv = *(const float4*)&g_b2p[col];
  float acc[8][4];
  #pragma unroll
  for(int r=0;r<8;r++){ acc[r][0]=bv.x; acc[r][1]=bv.y; acc[r][2]=bv.z; acc[r][3]=bv.w; }

  float4 wA[8], wB[8];
  #pragma unroll
  for(int u=0;u<8;u++) wA[u] = *(const float4*)&Wbase[(size_t)u*NGENP];

  for(int k0=0;k0<HID;k0+=16){
    #pragma unroll
    for(int u=0;u<8;u++) wB[u] = *(const float4*)&Wbase[(size_t)(k0+8+u)*NGENP];
    #pragma unroll
    for(int u=0;u<8;u++){
      float4 wv = wA[u];
      float4 h0 = *(const float4*)&hl[k0+u][0];
      float4 h1 = *(const float4*)&hl[k0+u][4];
      acc[0][0]+=h0.x*wv.x; acc[0][1]+=h0.x*wv.y; acc[0][2]+=h0.x*wv.z; acc[0][3]+=h0.x*wv.w;
      acc[1][0]+=h0.y*wv.x; acc[1][1]+=h0.y*wv.y; acc[1][2]+=h0.y*wv.z; acc[1][3]+=h0.y*wv.w;
      acc[2][0]+=h0.z*wv.x; acc[2][1]+=h0.z*wv.y; acc[2][2]+=h0.z*wv.z; acc[2][3]+=h0.z*wv.w;
      acc[3][0]+=h0.w*wv.x; acc[3][1]+=h0.w*wv.y; acc[3][2]+=h0.w*wv.z; acc[3][3]+=h0.w*wv.w;
      acc[4][0]+=h1.x*wv.x; acc[4][1]+=h1.x*wv.y; acc[4][2]+=h1.x*wv.z; acc[4][3]+=h1.x*wv.w;
      acc[5][0]+=h1.y*wv.x; acc[5][1]+=h1.y*wv.y; acc[5][2]+=h1.y*wv.z; acc[5][3]+=h1.y*wv.w;
      acc[6][0]+=h1.z*wv.x; acc[6][1]+=h1.z*wv.y; acc[6][2]+=h1.z*wv.z; acc[6][3]+=h1.z*wv.w;
      acc[7][0]+=h1.w*wv.x; acc[7][1]+=h1.w*wv.y; acc[7][2]+=h1.w*wv.z; acc[7][3]+=h1.w*wv.w;
    }
    if(k0+16 < HID){
      #pragma unroll
      for(int u=0;u<8;u++) wA[u] = *(const float4*)&Wbase[(size_t)(k0+16+u)*NGENP];
    }
    #pragma unroll
    for(int u=0;u<8;u++){
      float4 wv = wB[u];
      float4 h0 = *(const float4*)&hl[k0+8+u][0];
      float4 h1 = *(const float4*)&hl[k0+8+u][4];
      acc[0][0]+=h0.x*wv.x; acc[0][1]+=h0.x*wv.y; acc[0][2]+=h0.x*wv.z; acc[0][3]+=h0.x*wv.w;
      acc[1][0]+=h0.y*wv.x; acc[1][1]+=h0.y*wv.y; acc[1][2]+=h0.y*wv.z; acc[1][3]+=h0.y*wv.w;
      acc[2][0]+=h0.z*wv.x; acc[2][1]+=h0.z*wv.y; acc[2][2]+=h0.z*wv.z; acc[2][3]+=h0.z*wv.w;
      acc[3][0]+=h0.w*wv.x; acc[3][1]+=h0.w*wv.y; acc[3][2]+=h0.w*wv.z; acc[3][3]+=h0.w*wv.w;
      acc[4][0]+=h1.x*wv.x; acc[4][1]+=h1.x*wv.y; acc[4][2]+=h1.x*wv.z; acc[4][3]+=h1.x*wv.w;
      acc[5][0]+=h1.y*wv.x; acc[5][1]+=h1.y*wv.y; acc[5][2]+=h1.y*wv.z; acc[5][3]+=h1.y*wv.w;
      acc[6][0]+=h1.z*wv.x; acc[6][1]+=h1.z*wv.y; acc[6][2]+=h1.z*wv.z; acc[6][3]+=h1.z*wv.w;
      acc[7][0]+=h1.w*wv.x; acc[7][1]+=h1.w*wv.y; acc[7][2]+=h1.w*wv.z; acc[7][3]+=h1.w*wv.w;
    }
  }
  #pragma unroll
  for(int r=0;r<8;r++){
    float4 o = make_float4(acc[r][0],acc[r][1],acc[r][2],acc[r][3]);
    *(float4*)&g_theta[(size_t)(b0+r)*NGENP + col] = o;
  }
}

// -------- state: R11 body + recurrence state (vprev, vcur, ps) moved to REGISTERS.
// Each lane keeps row-i state c-redundantly (bitwise-equal across the 4 lanes of a
// row group); after the shfl-reduce all lanes hold the dot product, so each lane
// writes only its own replica v[c][i] -- the divergent if(c==0) tail is gone and
// ps never touches LDS inside the loop.  Arithmetic sequence unchanged -> bitwise
// identical output.
template<bool F32>
__device__ void state_body(const void* __restrict__ Aoff, const void* __restrict__ Boff,
                           const void* __restrict__ Ddiag,
                           const void* __restrict__ Wv1, const void* __restrict__ bv1,
                           const void* __restrict__ Wv2, const void* __restrict__ bv2,
                           void* __restrict__ out, char* sm){
  float*  th   = (float*)sm;                       // 16KB region, dead after WHT
  float*  HH   = (float*)(sm + 16384);             // 64*132 f
  typedef float2 rep_t[66];
  rep_t*  vrA  = (rep_t*)sm;                       // 2112 B
  rep_t*  vrB  = (rep_t*)(sm + 2112);              // 2112 B
  float2* ps   = (float2*)(sm + 4224);             // 512 B
  float2* coef = (float2*)(sm + 4736);             // 1280 B
  float*  rs   = (float*)(sm + 6016);              // 256 B
  float*  qacc = (float*)(sm + 6272);              // 64 B
  float*  s_inva = (float*)(sm + 6336);
  int*    s_K    = (int*)(sm + 6340);
  float*  hl   = (float*)(sm + 6400);              // 1KB   (fused vel)
  float (*part)[64][8] = (float(*)[64][8])(sm + 7424); // 8KB -> ends 15616
  float*  s2p  = (float*)(sm + 15616);             // 16 B (per-wave theta^2 partials)

  const int b = blockIdx.x, t = threadIdx.x;
  const int lane = t & 63, wav = t >> 6;

  float s2l = 0.f;
  for(int m=t;m<NGEN;m+=256){
    float v = g_theta[(size_t)b*NGENP+m];
    th[m] = v;
    s2l += v*v;
  }

  // ---- hoisted tail loads: latency hides under the WHT + Chebyshev phases ----
  float obs_d = 0.f, obs_a = 0.f, obs_b = 0.f;
  {
    int w = t/10, s = t%10;
    if(t<150){
      if(s<3)        obs_d = LD<F32>(Ddiag, w*4 + s + 1);
      else if(s>=4){ obs_a = LD<F32>(Aoff, w*6 + s-4);
                     obs_b = LD<F32>(Boff, w*6 + s-4); }
    }
  }
  float wv1h[NOBS], bv1h, bv2lo = 0.f, bv2hi = 0.f;
  if(!F32){
    bv1h = tof(((const bf16*)bv1)[t]);
    #pragma unroll
    for(int k=0;k<NOBS;k++) wv1h[k] = tof(((const bf16*)Wv1)[k*HID+t]);
    unsigned bp = ((const unsigned*)bv2)[t];
    bv2lo = blo(bp); bv2hi = bhi(bp);
  } else {
    bv1h = ((const float*)bv1)[t];
    #pragma unroll
    for(int k=0;k<NOBS;k++) wv1h[k] = ((const float*)Wv1)[k*HID+t];
  }
  __syncthreads();

  #pragma unroll 4
  for(int it=0; it<16; ++it){
    int d = (it<<2) | wav;
    unsigned td = (unsigned)(lane & d);
    unsigned tn = (unsigned)(lane & ~d) & 63u;
    unsigned w  = spread6((unsigned)d) + spread6(td) + 3u*spread6(tn);
    float thv = (w==0u) ? 0.f : th[w-1u];
    int ny = __popc(td) & 3;
    float gr = (ny==0)?  thv : (ny==2 ? -thv : 0.f);
    float gi = (ny==1)? -thv : (ny==3 ?  thv : 0.f);
    #pragma unroll
    for(int s=1;s<64;s<<=1){
      float pr = __shfl_xor(gr, s);
      float pi = __shfl_xor(gi, s);
      if(lane & s){ gr = pr - gr; gi = pi - gi; }
      else        { gr = gr + pr; gi = gi + pi; }
    }
    int j = lane ^ d;
    HH[lane*132 + 2*j]   = gr;
    HH[lane*132 + 2*j+1] = gi;
  }
  __syncthreads();          // th region dead; small buffers live there now

  const int i = t >> 2, c = t & 3, j0 = c*16;
  float hreg[32];
  float rsum = 0.f;
  #pragma unroll
  for(int jj=0;jj<16;jj+=2){
    float4 hv = *(const float4*)&HH[i*132 + 2*(j0+jj)];
    hreg[2*jj+0]=hv.x; hreg[2*jj+1]=hv.y; hreg[2*jj+2]=hv.z; hreg[2*jj+3]=hv.w;
    rsum += fabsf(hv.x)+fabsf(hv.y)+fabsf(hv.z)+fabsf(hv.w);
  }
  rsum += __shfl_xor(rsum,1);
  rsum += __shfl_xor(rsum,2);
  if(c==0) rs[i] = rsum;
  // full-wave reduce of theta^2 partial
  #pragma unroll
  for(int s=1;s<64;s<<=1) s2l += __shfl_xor(s2l, s);
  if(lane==0) s2p[wav] = s2l;
  __syncthreads();

  // ---- a = min(Gershgorin, 2.3*sqrt(sum theta^2)); Bessel coefficients ----
  if(t==0){
    float aG = 0.5f;
    for(int r=0;r<DIM;r++) aG = fmaxf(aG, rs[r]);
    float s2tot = s2p[0]+s2p[1]+s2p[2]+s2p[3];
    float a = fminf(aG, fmaxf(2.3f*sqrtf(s2tot), 0.5f));
    int K = (int)ceilf(a + 3.5f*cbrtf(a) + 4.f);
    if(K>150) K=150;
    float bkp=0.f, bk=1e-35f, snorm=0.f;
    for(int k=K+12;k>=1;--k){
      float bkm = (2.f*(float)k/a)*bk - bkp;
      int n = k-1;
      if(n<=K) coef[n].x = bkm;
      if((n&1)==0) snorm += (n==0?1.f:2.f)*bkm;
      bkp = bk; bk = bkm;
    }
    float invs = 1.f/snorm;
    for(int n=0;n<=K;n++){
      float cv = coef[n].x*invs*(n==0?1.f:2.f);
      int p = n&3;
      float cr = (p==0)? cv : (p==2 ? -cv : 0.f);
      float ci = (p==1)? cv : (p==3 ? -cv : 0.f);
      coef[n] = make_float2(cr,ci);
    }
    *s_K = K;
    *s_inva = 1.f/a;
  }
  __syncthreads();
  const float inva = *s_inva;
  const int K = *s_K;

  // ---- Chebyshev recurrence: state in registers, one replica write per lane ----
  rep_t* v0r = vrA;   // write target (holds dead v_{k-2} values)
  rep_t* v1r = vrB;   // current v_{k-1}, read by matvec
  float2 vprev, vcuri, psreg;
  {
    float2 w1 = make_float2(HH[i*132+0]*inva, HH[i*132+1]*inva);
    vprev = make_float2(i==0?1.f:0.f, 0.f);     // v0 = e0 (row i)
    vcuri = w1;                                  // v1 (row i)
    v1r[c][i] = w1;                              // each lane its own replica
    float2 c0 = coef[0], c1 = coef[1];
    psreg.x = (i==0?c0.x:0.f) + c1.x*w1.x - c1.y*w1.y;
    psreg.y = (i==0?c0.y:0.f) + c1.x*w1.y + c1.y*w1.x;
  }
  __syncthreads();

  for(int k=2;k<=K;k++){
    const float* vb = (const float*)&v1r[c][0];
    float yr=0.f, yi=0.f;
    #pragma unroll
    for(int jj=0;jj<16;jj+=2){
      float4 xv = *(const float4*)&vb[2*(j0+jj)];
      float hr0=hreg[2*jj], hi0=hreg[2*jj+1], hr1=hreg[2*jj+2], hi1=hreg[2*jj+3];
      yr += hr0*xv.x - hi0*xv.y;
      yi += hr0*xv.y + hi0*xv.x;
      yr += hr1*xv.z - hi1*xv.w;
      yi += hr1*xv.w + hi1*xv.z;
    }
    yr += __shfl_xor(yr,1); yr += __shfl_xor(yr,2);
    yi += __shfl_xor(yi,1); yi += __shfl_xor(yi,2);
    // all lanes hold the full dot product (bitwise-equal): pure-register update
    float2 vn = make_float2(2.f*inva*yr - vprev.x, 2.f*inva*yi - vprev.y);
    vprev = vcuri;
    vcuri = vn;
    float2 ck = coef[k];
    psreg.x += ck.x*vn.x - ck.y*vn.y;
    psreg.y += ck.x*vn.y + ck.y*vn.x;
    v0r[c][i] = vn;          // write own replica into the other buffer
    __syncthreads();
    rep_t* tmp = v0r; v0r = v1r; v1r = tmp;
  }

  if(c==0) ps[i] = psreg;    // publish final ps (all c hold identical bits)
  if(t<NOBS) qacc[t]=0.f;
  __syncthreads();

  if(t<150){
    int w = t/10, s = t%10;
    int posA = 5 - c_WA[w], posB = 5 - c_WB[w];
    float contrib = 0.f;
    bool have = false;
    if(s<4){
      int kk = s;
      if(kk<3){
        float val = 0.f;
        for(int r=0;r<16;r++){
          int idx = (((kk>>1)&1)<<posA) | ((kk&1)<<posB);
          int rb = 3;
          #pragma unroll
          for(int p=5;p>=0;--p){
            if(p==posA || p==posB) continue;
            idx |= ((r>>rb)&1)<<p;
            rb--;
          }
          float2 pv = ps[idx];
          val += pv.x*pv.x + pv.y*pv.y;
        }
        contrib = val*2.f*obs_d;
        have = true;
      }
    } else {
      int cc = s-4;
      int l = c_Lt[cc], kk = c_Kt[cc];
      float zr=0.f, zi=0.f;
      for(int r=0;r<16;r++){
        int idxk = (((kk>>1)&1)<<posA) | ((kk&1)<<posB);
        int idxl = (((l >>1)&1)<<posA) | ((l &1)<<posB);
        int rb = 3;
        #pragma unroll
        for(int p=5;p>=0;--p){
          if(p==posA || p==posB) continue;
          int bit = (r>>rb)&1;
          idxk |= bit<<p; idxl |= bit<<p;
          rb--;
        }
        float2 pk = ps[idxk], pl = ps[idxl];
        zr += pk.x*pl.x + pk.y*pl.y;
        zi += pk.y*pl.x - pk.x*pl.y;
      }
      contrib = 2.f*(zr*obs_a - zi*obs_b);
      have = true;
    }
    if(have) atomicAdd(&qacc[w], contrib);
  }
  __syncthreads();

  // ---------- FUSED vel head (both dtypes; Wv1/bv1/bv2 preloaded) ----------
  if(!F32){
    {
      float acc = bv1h;
      #pragma unroll
      for(int k=0;k<NOBS;k++) acc += qacc[k]*wv1h[k];
      hl[t] = silu(acc);
    }
    __syncthreads();
    const int rg = t >> 6;                     // k-chunk 0..3
    const uint4* w2v = (const uint4*)Wv2;      // row = 64 uint4 (512 cols)
    float a8[8] = {0.f,0.f,0.f,0.f,0.f,0.f,0.f,0.f};
    uint4 wvA[8], wvB[8];
    #pragma unroll
    for(int u=0;u<8;u++) wvA[u] = w2v[(size_t)(rg*64+u)*64 + lane];
    for(int kk=0; kk<64; kk+=16){
      #pragma unroll
      for(int u=0;u<8;u++) wvB[u] = w2v[(size_t)(rg*64+kk+8+u)*64 + lane];
      #pragma unroll
      for(int u=0;u<8;u++){
        float hk = hl[rg*64+kk+u];
        a8[0] += hk*blo(wvA[u].x); a8[1] += hk*bhi(wvA[u].x);
        a8[2] += hk*blo(wvA[u].y); a8[3] += hk*bhi(wvA[u].y);
        a8[4] += hk*blo(wvA[u].z); a8[5] += hk*bhi(wvA[u].z);
        a8[6] += hk*blo(wvA[u].w); a8[7] += hk*bhi(wvA[u].w);
      }
      if(kk+16 < 64){
        #pragma unroll
        for(int u=0;u<8;u++) wvA[u] = w2v[(size_t)(rg*64+kk+16+u)*64 + lane];
      }
      #pragma unroll
      for(int u=0;u<8;u++){
        float hk = hl[rg*64+kk+8+u];
        a8[0] += hk*blo(wvB[u].x); a8[1] += hk*bhi(wvB[u].x);
        a8[2] += hk*blo(wvB[u].y); a8[3] += hk*bhi(wvB[u].y);
        a8[4] += hk*blo(wvB[u].z); a8[5] += hk*bhi(wvB[u].z);
        a8[6] += hk*blo(wvB[u].w); a8[7] += hk*bhi(wvB[u].w);
      }
    }
    #pragma unroll
    for(int j=0;j<8;j++) part[rg][lane][j] = a8[j];
    __syncthreads();
    {
      int cA = 2*t, cB = 2*t+1;
      float vA = bv2lo;
      float vB = bv2hi;
      #pragma unroll
      for(int r2=0;r2<4;r2++){
        vA += part[r2][cA>>3][cA&7];
        vB += part[r2][cB>>3][cB&7];
      }
      bf16 ha = __float2bfloat16(vA), hb = __float2bfloat16(vB);
      unsigned pw = (unsigned)(*(unsigned short*)&ha) |
                    ((unsigned)(*(unsigned short*)&hb)<<16);
      ((unsigned*)out)[(size_t)b*(OUTDIM/2) + t] = pw;
    }
  } else {
    {
      float acc = bv1h;
      #pragma unroll
      for(int k=0;k<NOBS;k++) acc += qacc[k]*wv1h[k];
      hl[t] = silu(acc);
    }
    __syncthreads();
    #pragma unroll
    for(int oo=0;oo<2;oo++){
      int o = t + oo*256;
      float s0=0.f;
      for(int k=0;k<HID;k++) s0 += hl[k]*((const float*)Wv2)[(size_t)k*OUTDIM+o];
      ((float*)out)[(size_t)b*OUTDIM+o] = ((const float*)bv2)[o] + s0;
    }
  }
}

__global__ __launch_bounds__(256) void k_state(const void* Aoff,const void* Boff,const void* Dd,
                                               const void* Wv1,const void* bv1,
                                               const void* Wv2,const void* bv2, void* out){
  __shared__ __align__(16) char sm[50176];   // shared by both template paths
  if(g_isf32) state_body<true >(Aoff,Boff,Dd,Wv1,bv1,Wv2,bv2,out,sm);
  else        state_body<false>(Aoff,Boff,Dd,Wv1,bv1,Wv2,bv2,out,sm);
}

extern "C" void kernel_launch(void* const* d_in, const int* in_sizes, int n_in,
                              void* d_out, int out_size, void* d_ws, size_t ws_size,
                              hipStream_t stream){
  const void* x    = d_in[0];
  const void* W1   = d_in[1];
  const void* b1   = d_in[2];
  const void* W2   = d_in[3];
  const void* b2   = d_in[4];
  const void* Aoff = d_in[5];
  const void* Boff = d_in[6];
  const void* Dd   = d_in[7];
  const void* Wv1  = d_in[8];
  const void* bv1  = d_in[9];
  const void* Wv2  = d_in[10];
  const void* bv2  = d_in[11];
  // d_in[12] (pauli) unused: H_eff built analytically from the Pauli-word structure.

  k_pack <<<1024,256,0,stream>>>(W1,W2,b2);
  k_enc1 <<<BATCH,256,0,stream>>>(x,W1,b1);
  k_enc2 <<<256,256,0,stream>>>();
  k_state<<<BATCH,256,0,stream>>>(Aoff,Boff,Dd,Wv1,bv1,Wv2,bv2,d_out);
}

// Round 13
// 216.408 us; speedup vs baseline: 1.0605x; 1.0327x over previous
//
#include <hip/hip_runtime.h>
#include <hip/hip_bf16.h>

#define BATCH   512
#define INDIM   768
#define HID     256
#define NGEN    4095
#define NGENP   4096
#define NOBS    15
#define OUTDIM  512
#define DIM     64

typedef __hip_bfloat16 bf16;

// static device scratch
__device__ int      g_isf32;
__device__ float    g_theta[(size_t)BATCH*NGENP];     // padded stride 4096
__device__ float    g_h[(size_t)BATCH*HID];
__device__ float    g_W2p[(size_t)HID*NGENP];
__device__ float    g_b2p[NGENP];

__device__ __forceinline__ float tof(bf16 v){ return __bfloat162float(v); }
__device__ __forceinline__ float silu(float x){ return x / (1.f + __expf(-x)); }
__device__ __forceinline__ float blo(unsigned u){ return __uint_as_float(u<<16); }
__device__ __forceinline__ float bhi(unsigned u){ return __uint_as_float(u & 0xFFFF0000u); }

template<bool F32>
__device__ __forceinline__ float LD(const void* p, size_t i){
  if(F32) return ((const float*)p)[i];
  else    return tof(((const bf16*)p)[i]);
}

// put bit p of x at bit 2p (6-bit input)
__device__ __forceinline__ unsigned spread6(unsigned x){
  return (x&1u) | ((x&2u)<<1) | ((x&4u)<<2) | ((x&8u)<<3) | ((x&16u)<<4) | ((x&32u)<<5);
}

// per-block dtype sniff
__device__ __forceinline__ bool detect_f32(const unsigned* __restrict__ w1raw, int* red){
  const int t = threadIdx.x & (blockDim.x-1);
  const int lane = t & 63, wav = t >> 6;
  int c = 0;
  for(int i=t;i<1024;i+=(int)blockDim.x){
    unsigned ub = (w1raw[i]>>8) & 0x7Fu;
    if(ub>=0x30u && ub<=0x3Fu) c++;
  }
  #pragma unroll
  for(int s=1;s<64;s<<=1) c += __shfl_xor(c, s);
  if(lane==0) red[wav] = c;
  __syncthreads();
  int nw = (int)blockDim.x >> 6;
  int tot = 0;
  for(int w=0;w<nw;w++) tot += red[w];
  return tot < 512;
}

__constant__ int c_WA[15] = {0,0,0,0,0,1,1,1,1,2,2,2,3,3,4};
__constant__ int c_WB[15] = {1,2,3,4,5,2,3,4,5,3,4,5,4,5,5};
__constant__ int c_Lt[6]  = {1,2,2,3,3,3};
__constant__ int c_Kt[6]  = {0,0,1,0,1,2};

// ---- prep2: FUSED enc1 (blocks 0..511) + pack W2/b2 (blocks 512..1535).
// enc1 and pack touch disjoint inputs -> running them in one grid overlaps the
// latency-bound enc1 phase with the BW-bound pack streaming.  Bodies are the
// R9/R8-proven ones verbatim -> bitwise-identical h / W2p / b2p.
template<bool F32>
__device__ void enc1_role(const void* __restrict__ x, const void* __restrict__ W1,
                          const void* __restrict__ b1, float* xl){
  const int b = blockIdx.x, t = threadIdx.x;
  for(int k=t;k<INDIM;k+=256) xl[k] = LD<F32>(x,(size_t)b*INDIM+k);
  __syncthreads();
  float acc = 0.f;
  float wA[8], wB[8];
  #pragma unroll
  for(int u=0;u<8;u++) wA[u] = LD<F32>(W1,(size_t)u*HID+t);
  for(int k0=0;k0<INDIM;k0+=16){
    #pragma unroll
    for(int u=0;u<8;u++) wB[u] = LD<F32>(W1,(size_t)(k0+8+u)*HID+t);
    #pragma unroll
    for(int u=0;u<8;u++) acc += xl[k0+u]*wA[u];
    if(k0+16<INDIM){
      #pragma unroll
      for(int u=0;u<8;u++) wA[u] = LD<F32>(W1,(size_t)(k0+16+u)*HID+t);
    }
    #pragma unroll
    for(int u=0;u<8;u++) acc += xl[k0+8+u]*wB[u];
  }
  g_h[(size_t)b*HID+t] = silu(acc + LD<F32>(b1,t));
}

template<bool F32>
__device__ void pack_role(const void* __restrict__ W2, const void* __restrict__ b2){
  const size_t gid = (size_t)(blockIdx.x - BATCH)*256 + threadIdx.x;
  const size_t stride = (size_t)(gridDim.x - BATCH)*256;
  for(size_t i=gid;i<(size_t)HID*NGENP;i+=stride){
    size_t k = i>>12, c = i&4095;
    g_W2p[i] = (c<NGEN) ? LD<F32>(W2,k*NGEN+c) : 0.f;
  }
  for(size_t i=gid;i<NGENP;i+=stride) g_b2p[i] = (i<NGEN) ? LD<F32>(b2,i) : 0.f;
}

__global__ __launch_bounds__(256) void k_prep2(const void* x,const void* W1,const void* b1,
                                               const void* W2,const void* b2){
  __shared__ __align__(16) float xl[INDIM];
  __shared__ int red[4];
  bool isf32 = detect_f32((const unsigned*)W1, red);
  if(blockIdx.x==0 && threadIdx.x==0) g_isf32 = isf32 ? 1 : 0;
  if(blockIdx.x < BATCH){
    if(isf32) enc1_role<true >(x,W1,b1,xl);
    else      enc1_role<false>(x,W1,b1,xl);
  } else {
    if(isf32) pack_role<true >(W2,b2);
    else      pack_role<false>(W2,b2);
  }
}

// ---- enc2: theta = h@W2 + b2, register-tiled GEMM (R6-proven body) ----
__global__ __launch_bounds__(256) void k_enc2(){
  __shared__ __align__(16) float hl[HID][8];     // hl[k][r], 8KB, broadcast reads
  const int t  = threadIdx.x;
  const int b0 = (blockIdx.x>>2)*8;              // 64 row groups of 8
  const int c0 = (blockIdx.x&3)*1024;            // 4 col groups
  for(int i=t;i<8*HID;i+=256){
    int r = i>>8, k = i&255;
    hl[k][r] = g_h[(size_t)(b0+r)*HID + k];
  }
  __syncthreads();
  const int col = c0 + 4*t;
  const float* Wbase = g_W2p + col;
  float4 bv = *(const float4*)&g_b2p[col];
  float acc[8][4];
  #pragma unroll
  for(int r=0;r<8;r++){ acc[r][0]=bv.x; acc[r][1]=bv.y; acc[r][2]=bv.z; acc[r][3]=bv.w; }

  float4 wA[8], wB[8];
  #pragma unroll
  for(int u=0;u<8;u++) wA[u] = *(const float4*)&Wbase[(size_t)u*NGENP];

  for(int k0=0;k0<HID;k0+=16){
    #pragma unroll
    for(int u=0;u<8;u++) wB[u] = *(const float4*)&Wbase[(size_t)(k0+8+u)*NGENP];
    #pragma unroll
    for(int u=0;u<8;u++){
      float4 wv = wA[u];
      float4 h0 = *(const float4*)&hl[k0+u][0];
      float4 h1 = *(const float4*)&hl[k0+u][4];
      acc[0][0]+=h0.x*wv.x; acc[0][1]+=h0.x*wv.y; acc[0][2]+=h0.x*wv.z; acc[0][3]+=h0.x*wv.w;
      acc[1][0]+=h0.y*wv.x; acc[1][1]+=h0.y*wv.y; acc[1][2]+=h0.y*wv.z; acc[1][3]+=h0.y*wv.w;
      acc[2][0]+=h0.z*wv.x; acc[2][1]+=h0.z*wv.y; acc[2][2]+=h0.z*wv.z; acc[2][3]+=h0.z*wv.w;
      acc[3][0]+=h0.w*wv.x; acc[3][1]+=h0.w*wv.y; acc[3][2]+=h0.w*wv.z; acc[3][3]+=h0.w*wv.w;
      acc[4][0]+=h1.x*wv.x; acc[4][1]+=h1.x*wv.y; acc[4][2]+=h1.x*wv.z; acc[4][3]+=h1.x*wv.w;
      acc[5][0]+=h1.y*wv.x; acc[5][1]+=h1.y*wv.y; acc[5][2]+=h1.y*wv.z; acc[5][3]+=h1.y*wv.w;
      acc[6][0]+=h1.z*wv.x; acc[6][1]+=h1.z*wv.y; acc[6][2]+=h1.z*wv.z; acc[6][3]+=h1.z*wv.w;
      acc[7][0]+=h1.w*wv.x; acc[7][1]+=h1.w*wv.y; acc[7][2]+=h1.w*wv.z; acc[7][3]+=h1.w*wv.w;
    }
    if(k0+16 < HID){
      #pragma unroll
      for(int u=0;u<8;u++) wA[u] = *(const float4*)&Wbase[(size_t)(k0+16+u)*NGENP];
    }
    #pragma unroll
    for(int u=0;u<8;u++){
      float4 wv = wB[u];
      float4 h0 = *(const float4*)&hl[k0+8+u][0];
      float4 h1 = *(const float4*)&hl[k0+8+u][4];
      acc[0][0]+=h0.x*wv.x; acc[0][1]+=h0.x*wv.y; acc[0][2]+=h0.x*wv.z; acc[0][3]+=h0.x*wv.w;
      acc[1][0]+=h0.y*wv.x; acc[1][1]+=h0.y*wv.y; acc[1][2]+=h0.y*wv.z; acc[1][3]+=h0.y*wv.w;
      acc[2][0]+=h0.z*wv.x; acc[2][1]+=h0.z*wv.y; acc[2][2]+=h0.z*wv.z; acc[2][3]+=h0.z*wv.w;
      acc[3][0]+=h0.w*wv.x; acc[3][1]+=h0.w*wv.y; acc[3][2]+=h0.w*wv.z; acc[3][3]+=h0.w*wv.w;
      acc[4][0]+=h1.x*wv.x; acc[4][1]+=h1.x*wv.y; acc[4][2]+=h1.x*wv.z; acc[4][3]+=h1.x*wv.w;
      acc[5][0]+=h1.y*wv.x; acc[5][1]+=h1.y*wv.y; acc[5][2]+=h1.y*wv.z; acc[5][3]+=h1.y*wv.w;
      acc[6][0]+=h1.z*wv.x; acc[6][1]+=h1.z*wv.y; acc[6][2]+=h1.z*wv.z; acc[6][3]+=h1.z*wv.w;
      acc[7][0]+=h1.w*wv.x; acc[7][1]+=h1.w*wv.y; acc[7][2]+=h1.w*wv.z; acc[7][3]+=h1.w*wv.w;
    }
  }
  #pragma unroll
  for(int r=0;r<8;r++){
    float4 o = make_float4(acc[r][0],acc[r][1],acc[r][2],acc[r][3]);
    *(float4*)&g_theta[(size_t)(b0+r)*NGENP + col] = o;
  }
}

// -------- state: R12-proven body (register recurrence state, hoisted tail loads,
// moment-based a, K = a+3.5cbrt(a)+4) --------
template<bool F32>
__device__ void state_body(const void* __restrict__ Aoff, const void* __restrict__ Boff,
                           const void* __restrict__ Ddiag,
                           const void* __restrict__ Wv1, const void* __restrict__ bv1,
                           const void* __restrict__ Wv2, const void* __restrict__ bv2,
                           void* __restrict__ out, char* sm){
  float*  th   = (float*)sm;                       // 16KB region, dead after WHT
  float*  HH   = (float*)(sm + 16384);             // 64*132 f
  typedef float2 rep_t[66];
  rep_t*  vrA  = (rep_t*)sm;                       // 2112 B
  rep_t*  vrB  = (rep_t*)(sm + 2112);              // 2112 B
  float2* ps   = (float2*)(sm + 4224);             // 512 B
  float2* coef = (float2*)(sm + 4736);             // 1280 B
  float*  rs   = (float*)(sm + 6016);              // 256 B
  float*  qacc = (float*)(sm + 6272);              // 64 B
  float*  s_inva = (float*)(sm + 6336);
  int*    s_K    = (int*)(sm + 6340);
  float*  hl   = (float*)(sm + 6400);              // 1KB   (fused vel)
  float (*part)[64][8] = (float(*)[64][8])(sm + 7424); // 8KB -> ends 15616
  float*  s2p  = (float*)(sm + 15616);             // 16 B (per-wave theta^2 partials)

  const int b = blockIdx.x, t = threadIdx.x;
  const int lane = t & 63, wav = t >> 6;

  float s2l = 0.f;
  for(int m=t;m<NGEN;m+=256){
    float v = g_theta[(size_t)b*NGENP+m];
    th[m] = v;
    s2l += v*v;
  }

  // ---- hoisted tail loads: latency hides under the WHT + Chebyshev phases ----
  float obs_d = 0.f, obs_a = 0.f, obs_b = 0.f;
  {
    int w = t/10, s = t%10;
    if(t<150){
      if(s<3)        obs_d = LD<F32>(Ddiag, w*4 + s + 1);
      else if(s>=4){ obs_a = LD<F32>(Aoff, w*6 + s-4);
                     obs_b = LD<F32>(Boff, w*6 + s-4); }
    }
  }
  float wv1h[NOBS], bv1h, bv2lo = 0.f, bv2hi = 0.f;
  if(!F32){
    bv1h = tof(((const bf16*)bv1)[t]);
    #pragma unroll
    for(int k=0;k<NOBS;k++) wv1h[k] = tof(((const bf16*)Wv1)[k*HID+t]);
    unsigned bp = ((const unsigned*)bv2)[t];
    bv2lo = blo(bp); bv2hi = bhi(bp);
  } else {
    bv1h = ((const float*)bv1)[t];
    #pragma unroll
    for(int k=0;k<NOBS;k++) wv1h[k] = ((const float*)Wv1)[k*HID+t];
  }
  __syncthreads();

  #pragma unroll 4
  for(int it=0; it<16; ++it){
    int d = (it<<2) | wav;
    unsigned td = (unsigned)(lane & d);
    unsigned tn = (unsigned)(lane & ~d) & 63u;
    unsigned w  = spread6((unsigned)d) + spread6(td) + 3u*spread6(tn);
    float thv = (w==0u) ? 0.f : th[w-1u];
    int ny = __popc(td) & 3;
    float gr = (ny==0)?  thv : (ny==2 ? -thv : 0.f);
    float gi = (ny==1)? -thv : (ny==3 ?  thv : 0.f);
    #pragma unroll
    for(int s=1;s<64;s<<=1){
      float pr = __shfl_xor(gr, s);
      float pi = __shfl_xor(gi, s);
      if(lane & s){ gr = pr - gr; gi = pi - gi; }
      else        { gr = gr + pr; gi = gi + pi; }
    }
    int j = lane ^ d;
    HH[lane*132 + 2*j]   = gr;
    HH[lane*132 + 2*j+1] = gi;
  }
  __syncthreads();          // th region dead; small buffers live there now

  const int i = t >> 2, c = t & 3, j0 = c*16;
  float hreg[32];
  float rsum = 0.f;
  #pragma unroll
  for(int jj=0;jj<16;jj+=2){
    float4 hv = *(const float4*)&HH[i*132 + 2*(j0+jj)];
    hreg[2*jj+0]=hv.x; hreg[2*jj+1]=hv.y; hreg[2*jj+2]=hv.z; hreg[2*jj+3]=hv.w;
    rsum += fabsf(hv.x)+fabsf(hv.y)+fabsf(hv.z)+fabsf(hv.w);
  }
  rsum += __shfl_xor(rsum,1);
  rsum += __shfl_xor(rsum,2);
  if(c==0) rs[i] = rsum;
  // full-wave reduce of theta^2 partial
  #pragma unroll
  for(int s=1;s<64;s<<=1) s2l += __shfl_xor(s2l, s);
  if(lane==0) s2p[wav] = s2l;
  __syncthreads();

  // ---- a = min(Gershgorin, 2.3*sqrt(sum theta^2)); Bessel coefficients ----
  if(t==0){
    float aG = 0.5f;
    for(int r=0;r<DIM;r++) aG = fmaxf(aG, rs[r]);
    float s2tot = s2p[0]+s2p[1]+s2p[2]+s2p[3];
    float a = fminf(aG, fmaxf(2.3f*sqrtf(s2tot), 0.5f));
    int K = (int)ceilf(a + 3.5f*cbrtf(a) + 4.f);
    if(K>150) K=150;
    float bkp=0.f, bk=1e-35f, snorm=0.f;
    for(int k=K+12;k>=1;--k){
      float bkm = (2.f*(float)k/a)*bk - bkp;
      int n = k-1;
      if(n<=K) coef[n].x = bkm;
      if((n&1)==0) snorm += (n==0?1.f:2.f)*bkm;
      bkp = bk; bk = bkm;
    }
    float invs = 1.f/snorm;
    for(int n=0;n<=K;n++){
      float cv = coef[n].x*invs*(n==0?1.f:2.f);
      int p = n&3;
      float cr = (p==0)? cv : (p==2 ? -cv : 0.f);
      float ci = (p==1)? cv : (p==3 ? -cv : 0.f);
      coef[n] = make_float2(cr,ci);
    }
    *s_K = K;
    *s_inva = 1.f/a;
  }
  __syncthreads();
  const float inva = *s_inva;
  const int K = *s_K;

  // ---- Chebyshev recurrence: state in registers, one replica write per lane ----
  rep_t* v0r = vrA;   // write target (holds dead v_{k-2} values)
  rep_t* v1r = vrB;   // current v_{k-1}, read by matvec
  float2 vprev, vcuri, psreg;
  {
    float2 w1 = make_float2(HH[i*132+0]*inva, HH[i*132+1]*inva);
    vprev = make_float2(i==0?1.f:0.f, 0.f);     // v0 = e0 (row i)
    vcuri = w1;                                  // v1 (row i)
    v1r[c][i] = w1;                              // each lane its own replica
    float2 c0 = coef[0], c1 = coef[1];
    psreg.x = (i==0?c0.x:0.f) + c1.x*w1.x - c1.y*w1.y;
    psreg.y = (i==0?c0.y:0.f) + c1.x*w1.y + c1.y*w1.x;
  }
  __syncthreads();

  for(int k=2;k<=K;k++){
    const float* vb = (const float*)&v1r[c][0];
    float yr=0.f, yi=0.f;
    #pragma unroll
    for(int jj=0;jj<16;jj+=2){
      float4 xv = *(const float4*)&vb[2*(j0+jj)];
      float hr0=hreg[2*jj], hi0=hreg[2*jj+1], hr1=hreg[2*jj+2], hi1=hreg[2*jj+3];
      yr += hr0*xv.x - hi0*xv.y;
      yi += hr0*xv.y + hi0*xv.x;
      yr += hr1*xv.z - hi1*xv.w;
      yi += hr1*xv.w + hi1*xv.z;
    }
    yr += __shfl_xor(yr,1); yr += __shfl_xor(yr,2);
    yi += __shfl_xor(yi,1); yi += __shfl_xor(yi,2);
    // all lanes hold the full dot product (bitwise-equal): pure-register update
    float2 vn = make_float2(2.f*inva*yr - vprev.x, 2.f*inva*yi - vprev.y);
    vprev = vcuri;
    vcuri = vn;
    float2 ck = coef[k];
    psreg.x += ck.x*vn.x - ck.y*vn.y;
    psreg.y += ck.x*vn.y + ck.y*vn.x;
    v0r[c][i] = vn;          // write own replica into the other buffer
    __syncthreads();
    rep_t* tmp = v0r; v0r = v1r; v1r = tmp;
  }

  if(c==0) ps[i] = psreg;    // publish final ps (all c hold identical bits)
  if(t<NOBS) qacc[t]=0.f;
  __syncthreads();

  if(t<150){
    int w = t/10, s = t%10;
    int posA = 5 - c_WA[w], posB = 5 - c_WB[w];
    float contrib = 0.f;
    bool have = false;
    if(s<4){
      int kk = s;
      if(kk<3){
        float val = 0.f;
        for(int r=0;r<16;r++){
          int idx = (((kk>>1)&1)<<posA) | ((kk&1)<<posB);
          int rb = 3;
          #pragma unroll
          for(int p=5;p>=0;--p){
            if(p==posA || p==posB) continue;
            idx |= ((r>>rb)&1)<<p;
            rb--;
          }
          float2 pv = ps[idx];
          val += pv.x*pv.x + pv.y*pv.y;
        }
        contrib = val*2.f*obs_d;
        have = true;
      }
    } else {
      int cc = s-4;
      int l = c_Lt[cc], kk = c_Kt[cc];
      float zr=0.f, zi=0.f;
      for(int r=0;r<16;r++){
        int idxk = (((kk>>1)&1)<<posA) | ((kk&1)<<posB);
        int idxl = (((l >>1)&1)<<posA) | ((l &1)<<posB);
        int rb = 3;
        #pragma unroll
        for(int p=5;p>=0;--p){
          if(p==posA || p==posB) continue;
          int bit = (r>>rb)&1;
          idxk |= bit<<p; idxl |= bit<<p;
          rb--;
        }
        float2 pk = ps[idxk], pl = ps[idxl];
        zr += pk.x*pl.x + pk.y*pl.y;
        zi += pk.y*pl.x - pk.x*pl.y;
      }
      contrib = 2.f*(zr*obs_a - zi*obs_b);
      have = true;
    }
    if(have) atomicAdd(&qacc[w], contrib);
  }
  __syncthreads();

  // ---------- FUSED vel head (both dtypes; Wv1/bv1/bv2 preloaded) ----------
  if(!F32){
    {
      float acc = bv1h;
      #pragma unroll
      for(int k=0;k<NOBS;k++) acc += qacc[k]*wv1h[k];
      hl[t] = silu(acc);
    }
    __syncthreads();
    const int rg = t >> 6;                     // k-chunk 0..3
    const uint4* w2v = (const uint4*)Wv2;      // row = 64 uint4 (512 cols)
    float a8[8] = {0.f,0.f,0.f,0.f,0.f,0.f,0.f,0.f};
    uint4 wvA[8], wvB[8];
    #pragma unroll
    for(int u=0;u<8;u++) wvA[u] = w2v[(size_t)(rg*64+u)*64 + lane];
    for(int kk=0; kk<64; kk+=16){
      #pragma unroll
      for(int u=0;u<8;u++) wvB[u] = w2v[(size_t)(rg*64+kk+8+u)*64 + lane];
      #pragma unroll
      for(int u=0;u<8;u++){
        float hk = hl[rg*64+kk+u];
        a8[0] += hk*blo(wvA[u].x); a8[1] += hk*bhi(wvA[u].x);
        a8[2] += hk*blo(wvA[u].y); a8[3] += hk*bhi(wvA[u].y);
        a8[4] += hk*blo(wvA[u].z); a8[5] += hk*bhi(wvA[u].z);
        a8[6] += hk*blo(wvA[u].w); a8[7] += hk*bhi(wvA[u].w);
      }
      if(kk+16 < 64){
        #pragma unroll
        for(int u=0;u<8;u++) wvA[u] = w2v[(size_t)(rg*64+kk+16+u)*64 + lane];
      }
      #pragma unroll
      for(int u=0;u<8;u++){
        float hk = hl[rg*64+kk+8+u];
        a8[0] += hk*blo(wvB[u].x); a8[1] += hk*bhi(wvB[u].x);
        a8[2] += hk*blo(wvB[u].y); a8[3] += hk*bhi(wvB[u].y);
        a8[4] += hk*blo(wvB[u].z); a8[5] += hk*bhi(wvB[u].z);
        a8[6] += hk*blo(wvB[u].w); a8[7] += hk*bhi(wvB[u].w);
      }
    }
    #pragma unroll
    for(int j=0;j<8;j++) part[rg][lane][j] = a8[j];
    __syncthreads();
    {
      int cA = 2*t, cB = 2*t+1;
      float vA = bv2lo;
      float vB = bv2hi;
      #pragma unroll
      for(int r2=0;r2<4;r2++){
        vA += part[r2][cA>>3][cA&7];
        vB += part[r2][cB>>3][cB&7];
      }
      bf16 ha = __float2bfloat16(vA), hb = __float2bfloat16(vB);
      unsigned pw = (unsigned)(*(unsigned short*)&ha) |
                    ((unsigned)(*(unsigned short*)&hb)<<16);
      ((unsigned*)out)[(size_t)b*(OUTDIM/2) + t] = pw;
    }
  } else {
    {
      float acc = bv1h;
      #pragma unroll
      for(int k=0;k<NOBS;k++) acc += qacc[k]*wv1h[k];
      hl[t] = silu(acc);
    }
    __syncthreads();
    #pragma unroll
    for(int oo=0;oo<2;oo++){
      int o = t + oo*256;
      float s0=0.f;
      for(int k=0;k<HID;k++) s0 += hl[k]*((const float*)Wv2)[(size_t)k*OUTDIM+o];
      ((float*)out)[(size_t)b*OUTDIM+o] = ((const float*)bv2)[o] + s0;
    }
  }
}

__global__ __launch_bounds__(256) void k_state(const void* Aoff,const void* Boff,const void* Dd,
                                               const void* Wv1,const void* bv1,
                                               const void* Wv2,const void* bv2, void* out){
  __shared__ __align__(16) char sm[50176];   // shared by both template paths
  if(g_isf32) state_body<true >(Aoff,Boff,Dd,Wv1,bv1,Wv2,bv2,out,sm);
  else        state_body<false>(Aoff,Boff,Dd,Wv1,bv1,Wv2,bv2,out,sm);
}

extern "C" void kernel_launch(void* const* d_in, const int* in_sizes, int n_in,
                              void* d_out, int out_size, void* d_ws, size_t ws_size,
                              hipStream_t stream){
  const void* x    = d_in[0];
  const void* W1   = d_in[1];
  const void* b1   = d_in[2];
  const void* W2   = d_in[3];
  const void* b2   = d_in[4];
  const void* Aoff = d_in[5];
  const void* Boff = d_in[6];
  const void* Dd   = d_in[7];
  const void* Wv1  = d_in[8];
  const void* bv1  = d_in[9];
  const void* Wv2  = d_in[10];
  const void* bv2  = d_in[11];
  // d_in[12] (pauli) unused: H_eff built analytically from the Pauli-word structure.

  k_prep2<<<BATCH+1024,256,0,stream>>>(x,W1,b1,W2,b2);
  k_enc2 <<<256,256,0,stream>>>();
  k_state<<<BATCH,256,0,stream>>>(Aoff,Boff,Dd,Wv1,bv1,Wv2,bv2,d_out);
}